// Round 1
// 639.413 us; speedup vs baseline: 1.0042x; 1.0042x over previous
//
#include <hip/hip_runtime.h>
#include <hip/hip_bf16.h>
#include <math.h>
#include <stdint.h>

typedef __bf16 bf16;
typedef __attribute__((ext_vector_type(8))) __bf16 bf16x8;
typedef __attribute__((ext_vector_type(4))) __bf16 bf16x4;
typedef __attribute__((ext_vector_type(4))) float f32x4;
typedef __attribute__((ext_vector_type(16))) float f32x16;

static constexpr int cB = 2, cS = 2048, cCTX = 256, cD = 1024, cH = 16, cDH = 64, cDFF = 4096;

// async 16B global->LDS. HW semantics: dest = wave-uniform base + lane*16.
// Every call site MUST have lane i's lds ptr == base + 16*i bytes.
__device__ __forceinline__ void glds16(const bf16* g, bf16* l) {
  __builtin_amdgcn_global_load_lds(
      (const __attribute__((address_space(1))) void*)g,
      (__attribute__((address_space(3))) void*)l, 16, 0, 0);
}

// ---------------- batched transpose+convert: 8x fp32 [1024,1024] -> bf16 [1024,1024]^T ----------------
struct T8 { const float* s[8]; };
__global__ __launch_bounds__(256) void k_transpose8(T8 args, bf16* __restrict__ out) {
  __shared__ bf16 tile[64][66];
  const int n0 = blockIdx.x * 64, k0 = blockIdx.y * 64;
  const int z = blockIdx.z;
  const float* in = args.s[z];
  bf16* dst_base = out + (size_t)z * 1024 * 1024;
  const int t = threadIdx.x;
  const int r = t >> 2, cb = (t & 3) * 16;
  const float* src = in + (size_t)(k0 + r) * 1024 + n0 + cb;
#pragma unroll
  for (int q4 = 0; q4 < 4; ++q4) {
    f32x4 v = *(const f32x4*)(src + q4 * 4);
#pragma unroll
    for (int e = 0; e < 4; ++e) tile[r][cb + q4 * 4 + e] = (bf16)v[e];
  }
  __syncthreads();
  bf16* dst = dst_base + (size_t)(n0 + r) * 1024 + k0 + cb;
  bf16x8 o0, o1;
#pragma unroll
  for (int e = 0; e < 8; ++e) { o0[e] = tile[cb + e][r]; o1[e] = tile[cb + 8 + e][r]; }
  *(bf16x8*)(dst) = o0;
  *(bf16x8*)(dst + 8) = o1;
}

// ---------------- transpose+convert: fp32 [K,N] -> bf16 [N,K] (for ff weights) ----------------
__global__ __launch_bounds__(256) void k_transpose(const float* __restrict__ in,
                                                   bf16* __restrict__ out, int K, int N) {
  __shared__ bf16 tile[64][66];
  const int n0 = blockIdx.x * 64, k0 = blockIdx.y * 64;
  const int t = threadIdx.x;
  const int r = t >> 2, cb = (t & 3) * 16;
  const float* src = in + (size_t)(k0 + r) * N + n0 + cb;
#pragma unroll
  for (int q4 = 0; q4 < 4; ++q4) {
    f32x4 v = *(const f32x4*)(src + q4 * 4);
#pragma unroll
    for (int e = 0; e < 4; ++e) tile[r][cb + q4 * 4 + e] = (bf16)v[e];
  }
  __syncthreads();
  bf16* dst = out + (size_t)(n0 + r) * K + k0 + cb;
  bf16x8 o0, o1;
#pragma unroll
  for (int e = 0; e < 8; ++e) { o0[e] = tile[cb + e][r]; o1[e] = tile[cb + 8 + e][r]; }
  *(bf16x8*)(dst) = o0;
  *(bf16x8*)(dst + 8) = o1;
}

// ---------------- V transpose -> VT[(b*16+h)*64+d][kvlen] ----------------
__global__ __launch_bounds__(256) void k_vt(const bf16* __restrict__ V, int vstride,
                                            bf16* __restrict__ VT, int kvlen) {
  __shared__ bf16 tile[64][72];
  const int kt = blockIdx.x * 64, bh = blockIdx.y;
  const int b = bh >> 4, h = bh & 15;
  const int t = threadIdx.x, r = t >> 2, cb = (t & 3) * 16;
  const bf16* src = V + (size_t)(b * kvlen + kt + r) * vstride + h * 64 + cb;
  bf16x8 a0 = *(const bf16x8*)src;
  bf16x8 a1 = *(const bf16x8*)(src + 8);
#pragma unroll
  for (int e = 0; e < 8; ++e) { tile[r][cb + e] = a0[e]; tile[r][cb + 8 + e] = a1[e]; }
  __syncthreads();
  bf16* dst = VT + ((size_t)bh * 64 + r) * kvlen + kt + cb;
  bf16x8 o0, o1;
#pragma unroll
  for (int e = 0; e < 8; ++e) { o0[e] = tile[cb + e][r]; o1[e] = tile[cb + 8 + e][r]; }
  *(bf16x8*)(dst) = o0;
  *(bf16x8*)(dst + 8) = o1;
}

// ---------------- fp32 -> bf16 elementwise ----------------
__global__ __launch_bounds__(256) void k_f2b(const float* __restrict__ in, bf16* __restrict__ out) {
  const int base = (blockIdx.x * 256 + threadIdx.x) * 4;
  f32x4 v = *(const f32x4*)(in + base);
  bf16x4 o;
#pragma unroll
  for (int e = 0; e < 4; ++e) o[e] = (bf16)v[e];
  *(bf16x4*)(out + base) = o;
}

// ---------------- merged emb: emb_i = t @ W_i + b_i -> fp32 [3][2,2048] ----------------
struct EmbArgs { const float* w0; const float* w1; const float* w2;
                 const float* b0; const float* b1; const float* b2; };
__global__ __launch_bounds__(256) void k_emb3(const float* __restrict__ t, EmbArgs ea,
                                              float* __restrict__ emb) {
  const int which = blockIdx.y;
  const float* w = which == 0 ? ea.w0 : (which == 1 ? ea.w1 : ea.w2);
  const float* bias = which == 0 ? ea.b0 : (which == 1 ? ea.b1 : ea.b2);
  float* dst = emb + which * 4096;
  const int jj = threadIdx.x & 63;
  const int j = blockIdx.x * 64 + jj;
  const int kg = threadIdx.x >> 6;
  float a0 = 0.f, a1 = 0.f;
  for (int k = kg * 256; k < kg * 256 + 256; ++k) {
    float wv = w[(size_t)k * 2048 + j];
    a0 += t[k] * wv;
    a1 += t[1024 + k] * wv;
  }
  __shared__ float s0[4][64], s1[4][64];
  s0[kg][jj] = a0;
  s1[kg][jj] = a1;
  __syncthreads();
  if (threadIdx.x < 64) {
    dst[j] = s0[0][jj] + s0[1][jj] + s0[2][jj] + s0[3][jj] + bias[j];
    dst[2048 + j] = s1[0][jj] + s1[1][jj] + s1[2][jj] + s1[3][jj] + bias[j];
  }
}

// ---------------- AdaLN ----------------
__global__ __launch_bounds__(256) void k_adaln(const float* __restrict__ xres,
                                               const float* __restrict__ emb,
                                               bf16* __restrict__ h) {
  const int token = blockIdx.x;
  const int b = token >> 11;
  const float* x = xres + (size_t)token * 1024;
  const float* sc = emb + b * 2048;
  const int t = threadIdx.x;
  float v[4], s = 0.f, sq = 0.f;
#pragma unroll
  for (int i = 0; i < 4; ++i) {
    float u = x[t + 256 * i];
    v[i] = u; s += u; sq += u * u;
  }
#pragma unroll
  for (int off = 1; off < 64; off <<= 1) {
    s += __shfl_xor(s, off);
    sq += __shfl_xor(sq, off);
  }
  __shared__ float ss[4], ssq[4];
  const int wave = t >> 6;
  if ((t & 63) == 0) { ss[wave] = s; ssq[wave] = sq; }
  __syncthreads();
  const float S_ = ss[0] + ss[1] + ss[2] + ss[3];
  const float SQ = ssq[0] + ssq[1] + ssq[2] + ssq[3];
  const float mean = S_ * (1.f / 1024.f);
  const float var = SQ * (1.f / 1024.f) - mean * mean;
  const float rstd = rsqrtf(var + 1e-5f);
#pragma unroll
  for (int i = 0; i < 4; ++i) {
    const int c = t + 256 * i;
    float val = (v[i] - mean) * rstd * (1.f + sc[c]) + sc[1024 + c];
    h[(size_t)token * 1024 + c] = (bf16)val;
  }
}

// ---------------- GEMM (32x32x16 MFMA): C[M,N] = A[M,K] @ Bt[N,K]^T (+bias)(+res) ----------------
template <int TN>
__global__ __launch_bounds__(256) void k_gemm_t(const bf16* __restrict__ A,
                                                const bf16* __restrict__ Bt,
                                                bf16* Cb, float* Cf,
                                                const float* __restrict__ bias,
                                                const float* res,
                                                int M, int N, int K) {
  constexpr int CJ = TN / 64;  // 32-col MFMA tiles per wave (1 or 2)
  __shared__ bf16 As[2 * 128 * 32];
  __shared__ bf16 Bs[2 * TN * 32];
  const int m0 = blockIdx.y * 128, n0 = blockIdx.x * TN;
  const int tid = threadIdx.x;
  const int wave = tid >> 6, lane = tid & 63;
  const int l31 = lane & 31, hi8 = (lane >> 5) * 8;
  const int mw = (wave >> 1) * 64, nw = (wave & 1) * (TN / 2);
  f32x16 acc[2][CJ];
#pragma unroll
  for (int i = 0; i < 2; ++i)
#pragma unroll
    for (int j = 0; j < CJ; ++j) acc[i][j] = (f32x16)(0.f);

  const int r0 = tid >> 2, c0 = (tid & 3) << 3;
  const bf16* Ap = A + (size_t)(m0 + r0) * K + c0;
  const bf16* Bp = Bt + (size_t)(n0 + r0) * K + c0;
  bf16* lA = As + r0 * 32 + c0;
  bf16* lB = Bs + r0 * 32 + c0;

  for (int k0 = 0; k0 < K; k0 += 64) {
    __syncthreads();
    glds16(Ap + k0, lA);
    glds16(Ap + k0 + (size_t)64 * K, lA + 64 * 32);
    glds16(Ap + k0 + 32, lA + 128 * 32);
    glds16(Ap + k0 + 32 + (size_t)64 * K, lA + 192 * 32);
    glds16(Bp + k0, lB);
    if (TN == 128) glds16(Bp + k0 + (size_t)64 * K, lB + 64 * 32);
    glds16(Bp + k0 + 32, lB + TN * 32);
    if (TN == 128) glds16(Bp + k0 + 32 + (size_t)64 * K, lB + TN * 32 + 64 * 32);
    __syncthreads();
#pragma unroll
    for (int kp = 0; kp < 2; ++kp) {        // 32-col panel
      const bf16* Asp = As + kp * 128 * 32;
      const bf16* Bsp = Bs + kp * TN * 32;
#pragma unroll
      for (int kh = 0; kh < 2; ++kh) {      // 16-k half within panel
        bf16x8 af[2], bfr[CJ];
#pragma unroll
        for (int i = 0; i < 2; ++i)
          af[i] = *(const bf16x8*)(Asp + (mw + i * 32 + l31) * 32 + kh * 16 + hi8);
#pragma unroll
        for (int j = 0; j < CJ; ++j)
          bfr[j] = *(const bf16x8*)(Bsp + (nw + j * 32 + l31) * 32 + kh * 16 + hi8);
#pragma unroll
        for (int i = 0; i < 2; ++i)
#pragma unroll
          for (int j = 0; j < CJ; ++j)
            acc[i][j] = __builtin_amdgcn_mfma_f32_32x32x16_bf16(af[i], bfr[j], acc[i][j], 0, 0, 0);
      }
    }
  }

#pragma unroll
  for (int i = 0; i < 2; ++i) {
    const int rb = m0 + mw + i * 32 + 4 * (lane >> 5);
#pragma unroll
    for (int j = 0; j < CJ; ++j) {
      const int col = n0 + nw + j * 32 + l31;
      const float bv = bias ? bias[col] : 0.f;
#pragma unroll
      for (int reg = 0; reg < 16; ++reg) {
        const int row = rb + (reg & 3) + 8 * (reg >> 2);
        const size_t off = (size_t)row * N + col;
        float v2 = acc[i][j][reg] + bv;
        if (res) v2 += res[off];
        if (Cf) Cf[off] = v2;
        if (Cb) Cb[off] = (bf16)v2;
      }
    }
  }
}

// ---------------- FF1: 8-phase 256-row x (128a+128g col) GLU GEMM ----------------
// T3+T4 schedule: 2 K-tiles / 8 phases per iteration, one half-tile staged per
// phase, counted s_waitcnt vmcnt(6) only at phases 4 and 8 (3 half-tiles = 6
// loads in flight across raw s_barriers). T5 setprio around each 16-MFMA
// cluster. T1 bijective XCD swizzle (512 blocks % 8 == 0).
// LDS: [buf][khalf] panels of [256 rows][32 cols] bf16 -> each 16x16x32 MFMA
// fragment read is a contiguous 1024B block (16 rows x 64B) = conflict-free,
// so global_load_lds keeps its mandatory linear destination (no swizzle).
// GLU fusion: per-wave B rows interleave 32 a-cols + 32 gate-cols for the SAME
// output columns, so acc[m][0..1] (a) pairs with acc[m][2..3] (gate) in-lane.
__global__ __launch_bounds__(512, 2) void k_glu8(const bf16* __restrict__ A,
                                                 const bf16* __restrict__ Bt,
                                                 const float* __restrict__ bias,
                                                 bf16* __restrict__ C) {
  constexpr int K = 1024, NOUT = 4096, NT = K / 64, NIT = NT / 2;
  __shared__ __align__(16) bf16 sA[2 * 2 * 8192];   // [buf][khalf][256][32]
  __shared__ __align__(16) bf16 sB[2 * 2 * 8192];

  // 512 blocks -> 8 XCDs x 64; within an XCD: 4 n-strips x 16 m (m-fast so the
  // XCD's L2 holds its 4 B-panels, A panels stream).
  const int bid = blockIdx.x;
  const int xcd = bid & 7, bj = bid >> 3;
  const int n_idx = xcd * 4 + (bj >> 4);
  const int m_idx = bj & 15;
  const int m0 = m_idx * 256, n0 = n_idx * 128;

  const int tid = threadIdx.x;
  const int wid = tid >> 6, lane = tid & 63;
  const int l15 = lane & 15, hi = lane >> 4;
  const int wm = wid >> 2, wn = wid & 3;     // 2 x 4 wave grid

  // staging: each wave covers 32 rows of a [256][32] half-panel; 2 glds16 of
  // 1024B each (16 rows). lane covers row (lane>>2), 16B chunk (lane&3).
  const int srA = wid * 32 + (lane >> 2);
  const int scol = (lane & 3) * 8;
  const bf16* aS0 = A + (size_t)(m0 + srA) * K + scol;
  const bf16* aS1 = aS0 + (size_t)16 * K;
  auto grow = [&](int r) {   // B LDS row -> global Bt row (a/gate interleave)
    return n0 + (r >> 6) * 32 + (r & 31) + ((r & 32) ? NOUT : 0);
  };
  const bf16* bS0 = Bt + (size_t)grow(srA) * K + scol;
  const bf16* bS1 = Bt + (size_t)grow(srA + 16) * K + scol;
  bf16* aD = sA + wid * 1024 + lane * 8;
  bf16* bD = sB + wid * 1024 + lane * 8;
  const bf16* aF = sA + (wm * 128 + l15) * 32 + hi * 8;
  const bf16* bF = sB + (wn * 64 + l15) * 32 + hi * 8;

  f32x4 acc[8][4];
#pragma unroll
  for (int i = 0; i < 8; ++i)
#pragma unroll
    for (int n = 0; n < 4; ++n) acc[i][n] = (f32x4){0.f, 0.f, 0.f, 0.f};
  bf16x8 aq[4], bq[4];

#define STG_A(bb, kh, kt) do { \
    glds16(aS0 + (kt) * 64 + (kh) * 32, aD + ((bb) * 2 + (kh)) * 8192); \
    glds16(aS1 + (kt) * 64 + (kh) * 32, aD + ((bb) * 2 + (kh)) * 8192 + 512); } while (0)
#define STG_B(bb, kh, kt) do { \
    glds16(bS0 + (kt) * 64 + (kh) * 32, bD + ((bb) * 2 + (kh)) * 8192); \
    glds16(bS1 + (kt) * 64 + (kh) * 32, bD + ((bb) * 2 + (kh)) * 8192 + 512); } while (0)

#define PH(bb, kh, mh, STAGES, VMC) do { \
    if ((mh) == 0) { \
      _Pragma("unroll") \
      for (int nf = 0; nf < 4; ++nf) \
        bq[nf] = *(const bf16x8*)(bF + ((bb) * 2 + (kh)) * 8192 + nf * 512); \
    } \
    _Pragma("unroll") \
    for (int mi = 0; mi < 4; ++mi) \
      aq[mi] = *(const bf16x8*)(aF + ((bb) * 2 + (kh)) * 8192 + ((mh) * 4 + mi) * 512); \
    STAGES; \
    __builtin_amdgcn_s_barrier(); \
    asm volatile("s_waitcnt lgkmcnt(0)" ::: "memory"); \
    __builtin_amdgcn_sched_barrier(0); \
    __builtin_amdgcn_s_setprio(1); \
    _Pragma("unroll") \
    for (int mi = 0; mi < 4; ++mi) \
      _Pragma("unroll") \
      for (int nf = 0; nf < 4; ++nf) \
        acc[(mh) * 4 + mi][nf] = __builtin_amdgcn_mfma_f32_16x16x32_bf16( \
            aq[mi], bq[nf], acc[(mh) * 4 + mi][nf], 0, 0, 0); \
    __builtin_amdgcn_s_setprio(0); \
    VMC; \
    __builtin_amdgcn_s_barrier(); \
    __builtin_amdgcn_sched_barrier(0); \
  } while (0)

  // prologue: tile0 fully + tile1 {B-K0, A-K0, B-K1}; vmcnt(6) -> tile0 landed.
  STG_B(0, 0, 0); STG_A(0, 0, 0); STG_B(0, 1, 0); STG_A(0, 1, 0);
  STG_B(1, 0, 1); STG_A(1, 0, 1); STG_B(1, 1, 1);
  asm volatile("s_waitcnt vmcnt(6)" ::: "memory");
  __builtin_amdgcn_s_barrier();
  __builtin_amdgcn_sched_barrier(0);

  for (int it = 0; it < NIT; ++it) {
    const int T = 2 * it;
    const int t2 = (T + 2 < NT) ? (T + 2) : 0;   // clamped dead prefetch on tail
    const int t3 = (T + 3 < NT) ? (T + 3) : 0;
    PH(0, 0, 0, STG_A(1, 1, T + 1), );
    PH(0, 0, 1, STG_B(0, 0, t2), );
    PH(0, 1, 0, STG_A(0, 0, t2), );
    PH(0, 1, 1, STG_B(0, 1, t2), asm volatile("s_waitcnt vmcnt(6)" ::: "memory"));
    PH(1, 0, 0, STG_A(0, 1, t2), );
    PH(1, 0, 1, STG_B(1, 0, t3), );
    PH(1, 1, 0, STG_A(1, 0, t3), );
    PH(1, 1, 1, STG_B(1, 1, t3), asm volatile("s_waitcnt vmcnt(6)" ::: "memory"));
  }
#undef PH
#undef STG_A
#undef STG_B

  // GLU epilogue: acc[.][0..1] = a, acc[.][2..3] = gate for the same columns.
#pragma unroll
  for (int mi = 0; mi < 8; ++mi) {
    const int row = m0 + wm * 128 + mi * 16 + hi * 4;
#pragma unroll
    for (int nf = 0; nf < 2; ++nf) {
      const int col = n0 + wn * 32 + nf * 16 + l15;
      const float bav = bias[col], bgv = bias[NOUT + col];
#pragma unroll
      for (int r = 0; r < 4; ++r) {
        float a = acc[mi][nf][r] + bav;
        float g = acc[mi][nf + 2][r] + bgv;
        float ge = 0.5f * g * (1.0f + erff(g * 0.70710678118654752f));
        C[(size_t)(row + r) * NOUT + col] = (bf16)(a * ge);
      }
    }
  }
}

// ---------------- flash attention, fixed-max softmax, 128 Q-rows/block ----------------
__global__ __launch_bounds__(256) void k_attn(const bf16* __restrict__ Qp, int qstride,
                                              const bf16* __restrict__ Kp, int kstride,
                                              const bf16* __restrict__ VTp,
                                              bf16* __restrict__ Op, int kvlen) {
  const int qt = blockIdx.x * 128;
  const int hd = blockIdx.y;
  const int b = blockIdx.z;
  const int tid = threadIdx.x;
  const int wave = tid >> 6, lane = tid & 63;
  const int quad = lane >> 4, l16 = lane & 15;

  __shared__ __align__(16) bf16 Ks[64 * 64];
  __shared__ __align__(16) bf16 Vs[64 * 64];
  __shared__ __align__(16) bf16 Ps[4][32 * 72];

  bf16x8 qf[2][2];
#pragma unroll
  for (int g = 0; g < 2; ++g) {
    const bf16* qrow = Qp + (size_t)(b * cS + qt + wave * 32 + g * 16 + l16) * qstride + hd * 64;
#pragma unroll
    for (int c = 0; c < 2; ++c) {
      bf16x8 raw = *(const bf16x8*)(qrow + c * 32 + quad * 8);
#pragma unroll
      for (int e = 0; e < 8; ++e) qf[g][c][e] = (bf16)((float)raw[e] * 0.125f);
    }
  }

  float l_part[2][4] = {{0.f, 0.f, 0.f, 0.f}, {0.f, 0.f, 0.f, 0.f}};
  f32x4 o_acc[2][4];
#pragma unroll
  for (int g = 0; g < 2; ++g)
#pragma unroll
    for (int n = 0; n < 4; ++n) o_acc[g][n] = (f32x4){0.f, 0.f, 0.f, 0.f};

  const int lrow = wave * 16 + (lane >> 3);
  const int lcol = (lane & 7) * 8;
  const bf16* kbase = Kp + (size_t)(b * kvlen + lrow) * kstride + hd * 64 + lcol;
  const bf16* vbase = VTp + ((size_t)((b * 16 + hd) * 64 + lrow)) * kvlen + lcol;
  bf16* lk = Ks + lrow * 64 + lcol;
  bf16* lv = Vs + lrow * 64 + lcol;

  for (int kt = 0; kt < kvlen; kt += 64) {
    __syncthreads();
    const bf16* kg = kbase + (size_t)kt * kstride;
    glds16(kg, lk);
    glds16(kg + (size_t)8 * kstride, lk + 8 * 64);
    glds16(vbase + kt, lv);
    glds16(vbase + kt + (size_t)8 * kvlen, lv + 8 * 64);
    __syncthreads();

    f32x4 s[2][4];
#pragma unroll
    for (int g = 0; g < 2; ++g)
#pragma unroll
      for (int t = 0; t < 4; ++t) s[g][t] = (f32x4){0.f, 0.f, 0.f, 0.f};
#pragma unroll
    for (int t = 0; t < 4; ++t)
#pragma unroll
      for (int c = 0; c < 2; ++c) {
        bf16x8 kf = *(const bf16x8*)(Ks + (t * 16 + l16) * 64 + c * 32 + quad * 8);
#pragma unroll
        for (int g = 0; g < 2; ++g)
          s[g][t] = __builtin_amdgcn_mfma_f32_16x16x32_bf16(qf[g][c], kf, s[g][t], 0, 0, 0);
      }

#pragma unroll
    for (int g = 0; g < 2; ++g)
#pragma unroll
      for (int t = 0; t < 4; ++t)
#pragma unroll
        for (int r = 0; r < 4; ++r) {
          float p = __expf(s[g][t][r]);
          Ps[wave][(g * 16 + quad * 4 + r) * 72 + t * 16 + l16] = (bf16)p;
          l_part[g][r] += p;
        }

    bf16x8 pf[2][2];
#pragma unroll
    for (int g = 0; g < 2; ++g)
#pragma unroll
      for (int c = 0; c < 2; ++c)
        pf[g][c] = *(const bf16x8*)(&Ps[wave][(g * 16 + l16) * 72 + c * 32 + quad * 8]);
#pragma unroll
    for (int n = 0; n < 4; ++n)
#pragma unroll
      for (int c = 0; c < 2; ++c) {
        bf16x8 vf = *(const bf16x8*)(Vs + (n * 16 + l16) * 64 + c * 32 + quad * 8);
#pragma unroll
        for (int g = 0; g < 2; ++g)
          o_acc[g][n] = __builtin_amdgcn_mfma_f32_16x16x32_bf16(pf[g][c], vf, o_acc[g][n], 0, 0, 0);
      }
  }

#pragma unroll
  for (int g = 0; g < 2; ++g) {
    float rl[4];
#pragma unroll
    for (int r = 0; r < 4; ++r) {
      float v = l_part[g][r];
      v += __shfl_xor(v, 1);
      v += __shfl_xor(v, 2);
      v += __shfl_xor(v, 4);
      v += __shfl_xor(v, 8);
      rl[r] = 1.f / v;
    }
#pragma unroll
    for (int n = 0; n < 4; ++n)
#pragma unroll
      for (int r = 0; r < 4; ++r) {
        const int srow = qt + wave * 32 + g * 16 + quad * 4 + r;
        const int d = n * 16 + l16;
        Op[(size_t)(b * cS + srow) * 1024 + hd * 64 + d] = (bf16)(o_acc[g][n][r] * rl[r]);
      }
  }
}

// ---------------- launch ----------------
extern "C" void kernel_launch(void* const* d_in, const int* in_sizes, int n_in,
                              void* d_out, int out_size, void* d_ws, size_t ws_size,
                              hipStream_t stream) {
  const float* x    = (const float*)d_in[0];
  const float* tt   = (const float*)d_in[1];
  const float* ctx  = (const float*)d_in[2];
  const float* fw1  = (const float*)d_in[13];
  const float* fb1  = (const float*)d_in[14];
  const float* fw2  = (const float*)d_in[15];
  const float* fb2  = (const float*)d_in[16];
  const float* a1bo = (const float*)d_in[7];
  const float* a2bo = (const float*)d_in[12];

  char* ws = (char*)d_ws;
  const size_t MB = 1ull << 20;
  // 8 square transposed weights packed: [q1,k1,v1,o1,q2,k2,v2,o2] x 2 MB
  bf16* wsq   = (bf16*)(ws + 0 * MB);
  bf16* wqkv1 = wsq;                               // mats 0-2
  bf16* wto1  = (bf16*)(ws + 6 * MB);              // mat 3
  bf16* wtq2  = (bf16*)(ws + 8 * MB);              // mat 4
  bf16* wkv2w = (bf16*)(ws + 10 * MB);             // mats 5-6
  bf16* wto2  = (bf16*)(ws + 14 * MB);             // mat 7
  bf16* wtf1  = (bf16*)(ws + 16 * MB);             // [8192,1024], 16 MB
  bf16* wtf2  = (bf16*)(ws + 32 * MB);             // [1024,4096], 8 MB
  float* emb  = (float*)(ws + 40 * MB);            // 3 x [2,2048]
  float* emb1 = emb, *emb2 = emb + 4096, *emb3 = emb + 8192;
  bf16* ctxb  = (bf16*)(ws + 40 * MB + 262144);    // [512,1024], 1 MB
  float* xres = (float*)(ws + 42 * MB);            // fp32 residual, 16 MB
  bf16* h     = (bf16*)(ws + 58 * MB);             // 8 MB
  bf16* ao    = h;
  bf16* qkv   = (bf16*)(ws + 66 * MB);             // [4096,3072], 24 MB
  bf16* q2    = qkv;
  bf16* vT1   = (bf16*)(ws + 90 * MB);             // [32*64,2048], 8 MB
  bf16* kv2   = (bf16*)(ws + 0 * MB);              // [512,2048], 2 MB (aliases dead mats 0-1)
  bf16* vT2   = (bf16*)(ws + 2 * MB);              // [32*64,256], 1 MB (aliases dead mat 1)
  bf16* g     = (bf16*)(ws + 66 * MB);             // [4096,4096], 32 MB
  float* out  = (float*)d_out;

  const dim3 blk(256);

  T8 t8;
  t8.s[0] = (const float*)d_in[3];   // a1wq
  t8.s[1] = (const float*)d_in[4];   // a1wk
  t8.s[2] = (const float*)d_in[5];   // a1wv
  t8.s[3] = (const float*)d_in[6];   // a1wo
  t8.s[4] = (const float*)d_in[8];   // a2wq
  t8.s[5] = (const float*)d_in[9];   // a2wk
  t8.s[6] = (const float*)d_in[10];  // a2wv
  t8.s[7] = (const float*)d_in[11];  // a2wo
  k_transpose8<<<dim3(16, 16, 8), blk, 0, stream>>>(t8, wsq);
  k_transpose<<<dim3(128, 16), blk, 0, stream>>>(fw1, wtf1, 1024, 8192);
  k_transpose<<<dim3(16, 64), blk, 0, stream>>>(fw2, wtf2, 4096, 1024);

  EmbArgs ea;
  ea.w0 = (const float*)d_in[17]; ea.b0 = (const float*)d_in[18];
  ea.w1 = (const float*)d_in[19]; ea.b1 = (const float*)d_in[20];
  ea.w2 = (const float*)d_in[21]; ea.b2 = (const float*)d_in[22];
  k_emb3<<<dim3(32, 3), blk, 0, stream>>>(tt, ea, emb);
  k_f2b<<<512, blk, 0, stream>>>(ctx, ctxb);

  // ---- block 1: self-attention ----
  k_adaln<<<4096, blk, 0, stream>>>(x, emb1, h);
  k_gemm_t<128><<<dim3(24, 32), blk, 0, stream>>>(h, wqkv1, qkv, nullptr, nullptr, nullptr, 4096, 3072, 1024);
  k_vt<<<dim3(32, 32), blk, 0, stream>>>(qkv + 2048, 3072, vT1, 2048);
  k_attn<<<dim3(16, 16, 2), blk, 0, stream>>>(qkv, 3072, qkv + 1024, 3072, vT1, ao, 2048);
  k_gemm_t<64><<<dim3(16, 32), blk, 0, stream>>>(ao, wto1, nullptr, xres, a1bo, x, 4096, 1024, 1024);

  // ---- block 2: cross-attention ----
  k_adaln<<<4096, blk, 0, stream>>>(xres, emb2, h);
  k_gemm_t<64><<<dim3(16, 32), blk, 0, stream>>>(h, wtq2, q2, nullptr, nullptr, nullptr, 4096, 1024, 1024);
  k_gemm_t<128><<<dim3(16, 4), blk, 0, stream>>>(ctxb, wkv2w, kv2, nullptr, nullptr, nullptr, 512, 2048, 1024);
  k_vt<<<dim3(4, 32), blk, 0, stream>>>(kv2 + 1024, 2048, vT2, 256);
  k_attn<<<dim3(16, 16, 2), blk, 0, stream>>>(q2, 1024, kv2, 2048, vT2, ao, 256);
  k_gemm_t<64><<<dim3(16, 32), blk, 0, stream>>>(ao, wto2, nullptr, xres, a2bo, xres, 4096, 1024, 1024);

  // ---- block 3: gated-GELU FFN ----
  k_adaln<<<4096, blk, 0, stream>>>(xres, emb3, h);
  k_glu8<<<dim3(512), dim3(512), 0, stream>>>(h, wtf1, fb1, g);
  k_gemm_t<64><<<dim3(16, 32), blk, 0, stream>>>(g, wtf2, nullptr, out, fb2, xres, 4096, 1024, 4096);
}

// Round 2
// 625.129 us; speedup vs baseline: 1.0271x; 1.0228x over previous
//
#include <hip/hip_runtime.h>
#include <hip/hip_bf16.h>
#include <math.h>
#include <stdint.h>

typedef __bf16 bf16;
typedef __attribute__((ext_vector_type(8))) __bf16 bf16x8;
typedef __attribute__((ext_vector_type(4))) __bf16 bf16x4;
typedef __attribute__((ext_vector_type(4))) float f32x4;
typedef __attribute__((ext_vector_type(16))) float f32x16;

static constexpr int cB = 2, cS = 2048, cCTX = 256, cD = 1024, cH = 16, cDH = 64, cDFF = 4096;

// async 16B global->LDS. HW semantics: dest = wave-uniform base + lane*16.
// Every call site MUST have lane i's lds ptr == base + 16*i bytes.
__device__ __forceinline__ void glds16(const bf16* g, bf16* l) {
  __builtin_amdgcn_global_load_lds(
      (const __attribute__((address_space(1))) void*)g,
      (__attribute__((address_space(3))) void*)l, 16, 0, 0);
}

// ---------------- batched transpose+convert: 8x fp32 [1024,1024] -> bf16 [1024,1024]^T ----------------
struct T8 { const float* s[8]; };
__global__ __launch_bounds__(256) void k_transpose8(T8 args, bf16* __restrict__ out) {
  __shared__ bf16 tile[64][66];
  const int n0 = blockIdx.x * 64, k0 = blockIdx.y * 64;
  const int z = blockIdx.z;
  const float* in = args.s[z];
  bf16* dst_base = out + (size_t)z * 1024 * 1024;
  const int t = threadIdx.x;
  const int r = t >> 2, cb = (t & 3) * 16;
  const float* src = in + (size_t)(k0 + r) * 1024 + n0 + cb;
#pragma unroll
  for (int q4 = 0; q4 < 4; ++q4) {
    f32x4 v = *(const f32x4*)(src + q4 * 4);
#pragma unroll
    for (int e = 0; e < 4; ++e) tile[r][cb + q4 * 4 + e] = (bf16)v[e];
  }
  __syncthreads();
  bf16* dst = dst_base + (size_t)(n0 + r) * 1024 + k0 + cb;
  bf16x8 o0, o1;
#pragma unroll
  for (int e = 0; e < 8; ++e) { o0[e] = tile[cb + e][r]; o1[e] = tile[cb + 8 + e][r]; }
  *(bf16x8*)(dst) = o0;
  *(bf16x8*)(dst + 8) = o1;
}

// ---------------- transpose+convert: fp32 [K,N] -> bf16 [N,K] (for ff weights) ----------------
__global__ __launch_bounds__(256) void k_transpose(const float* __restrict__ in,
                                                   bf16* __restrict__ out, int K, int N) {
  __shared__ bf16 tile[64][66];
  const int n0 = blockIdx.x * 64, k0 = blockIdx.y * 64;
  const int t = threadIdx.x;
  const int r = t >> 2, cb = (t & 3) * 16;
  const float* src = in + (size_t)(k0 + r) * N + n0 + cb;
#pragma unroll
  for (int q4 = 0; q4 < 4; ++q4) {
    f32x4 v = *(const f32x4*)(src + q4 * 4);
#pragma unroll
    for (int e = 0; e < 4; ++e) tile[r][cb + q4 * 4 + e] = (bf16)v[e];
  }
  __syncthreads();
  bf16* dst = out + (size_t)(n0 + r) * K + k0 + cb;
  bf16x8 o0, o1;
#pragma unroll
  for (int e = 0; e < 8; ++e) { o0[e] = tile[cb + e][r]; o1[e] = tile[cb + 8 + e][r]; }
  *(bf16x8*)(dst) = o0;
  *(bf16x8*)(dst + 8) = o1;
}

// ---------------- V transpose -> VT[(b*16+h)*64+d][kvlen] ----------------
__global__ __launch_bounds__(256) void k_vt(const bf16* __restrict__ V, int vstride,
                                            bf16* __restrict__ VT, int kvlen) {
  __shared__ bf16 tile[64][72];
  const int kt = blockIdx.x * 64, bh = blockIdx.y;
  const int b = bh >> 4, h = bh & 15;
  const int t = threadIdx.x, r = t >> 2, cb = (t & 3) * 16;
  const bf16* src = V + (size_t)(b * kvlen + kt + r) * vstride + h * 64 + cb;
  bf16x8 a0 = *(const bf16x8*)src;
  bf16x8 a1 = *(const bf16x8*)(src + 8);
#pragma unroll
  for (int e = 0; e < 8; ++e) { tile[r][cb + e] = a0[e]; tile[r][cb + 8 + e] = a1[e]; }
  __syncthreads();
  bf16* dst = VT + ((size_t)bh * 64 + r) * kvlen + kt + cb;
  bf16x8 o0, o1;
#pragma unroll
  for (int e = 0; e < 8; ++e) { o0[e] = tile[cb + e][r]; o1[e] = tile[cb + 8 + e][r]; }
  *(bf16x8*)(dst) = o0;
  *(bf16x8*)(dst + 8) = o1;
}

// ---------------- fp32 -> bf16 elementwise ----------------
__global__ __launch_bounds__(256) void k_f2b(const float* __restrict__ in, bf16* __restrict__ out) {
  const int base = (blockIdx.x * 256 + threadIdx.x) * 4;
  f32x4 v = *(const f32x4*)(in + base);
  bf16x4 o;
#pragma unroll
  for (int e = 0; e < 4; ++e) o[e] = (bf16)v[e];
  *(bf16x4*)(out + base) = o;
}

// ---------------- merged emb: emb_i = t @ W_i + b_i -> fp32 [3][2,2048] ----------------
struct EmbArgs { const float* w0; const float* w1; const float* w2;
                 const float* b0; const float* b1; const float* b2; };
__global__ __launch_bounds__(256) void k_emb3(const float* __restrict__ t, EmbArgs ea,
                                              float* __restrict__ emb) {
  const int which = blockIdx.y;
  const float* w = which == 0 ? ea.w0 : (which == 1 ? ea.w1 : ea.w2);
  const float* bias = which == 0 ? ea.b0 : (which == 1 ? ea.b1 : ea.b2);
  float* dst = emb + which * 4096;
  const int jj = threadIdx.x & 63;
  const int j = blockIdx.x * 64 + jj;
  const int kg = threadIdx.x >> 6;
  float a0 = 0.f, a1 = 0.f;
  for (int k = kg * 256; k < kg * 256 + 256; ++k) {
    float wv = w[(size_t)k * 2048 + j];
    a0 += t[k] * wv;
    a1 += t[1024 + k] * wv;
  }
  __shared__ float s0[4][64], s1[4][64];
  s0[kg][jj] = a0;
  s1[kg][jj] = a1;
  __syncthreads();
  if (threadIdx.x < 64) {
    dst[j] = s0[0][jj] + s0[1][jj] + s0[2][jj] + s0[3][jj] + bias[j];
    dst[2048 + j] = s1[0][jj] + s1[1][jj] + s1[2][jj] + s1[3][jj] + bias[j];
  }
}

// ---------------- AdaLN ----------------
__global__ __launch_bounds__(256) void k_adaln(const float* __restrict__ xres,
                                               const float* __restrict__ emb,
                                               bf16* __restrict__ h) {
  const int token = blockIdx.x;
  const int b = token >> 11;
  const float* x = xres + (size_t)token * 1024;
  const float* sc = emb + b * 2048;
  const int t = threadIdx.x;
  float v[4], s = 0.f, sq = 0.f;
#pragma unroll
  for (int i = 0; i < 4; ++i) {
    float u = x[t + 256 * i];
    v[i] = u; s += u; sq += u * u;
  }
#pragma unroll
  for (int off = 1; off < 64; off <<= 1) {
    s += __shfl_xor(s, off);
    sq += __shfl_xor(sq, off);
  }
  __shared__ float ss[4], ssq[4];
  const int wave = t >> 6;
  if ((t & 63) == 0) { ss[wave] = s; ssq[wave] = sq; }
  __syncthreads();
  const float S_ = ss[0] + ss[1] + ss[2] + ss[3];
  const float SQ = ssq[0] + ssq[1] + ssq[2] + ssq[3];
  const float mean = S_ * (1.f / 1024.f);
  const float var = SQ * (1.f / 1024.f) - mean * mean;
  const float rstd = rsqrtf(var + 1e-5f);
#pragma unroll
  for (int i = 0; i < 4; ++i) {
    const int c = t + 256 * i;
    float val = (v[i] - mean) * rstd * (1.f + sc[c]) + sc[1024 + c];
    h[(size_t)token * 1024 + c] = (bf16)val;
  }
}

// ---------------- GEMM (32x32x16 MFMA): C[M,N] = A[M,K] @ Bt[N,K]^T (+bias)(+res) ----------------
// DB=1: original 2-barrier structure (for TN=128 sites at 3+ blocks/CU).
// DB=2: minimum-2-phase (T3 minimum): stage(buf^1) issued BEFORE compute(buf),
//       one vmcnt(0)+barrier per K-step -> staged loads fly under the MFMA.
//       For the 2-blocks/CU sites (wo/ff2) where TLP alone can't hide latency.
template <int TN, int DB>
__global__ __launch_bounds__(256) void k_gemm_t(const bf16* __restrict__ A,
                                                const bf16* __restrict__ Bt,
                                                bf16* Cb, float* Cf,
                                                const float* __restrict__ bias,
                                                const float* res,
                                                int M, int N, int K) {
  constexpr int CJ = TN / 64;  // 32-col MFMA tiles per wave (1 or 2)
  __shared__ bf16 As[DB][2 * 128 * 32];
  __shared__ bf16 Bs[DB][2 * TN * 32];
  const int m0 = blockIdx.y * 128, n0 = blockIdx.x * TN;
  const int tid = threadIdx.x;
  const int wave = tid >> 6, lane = tid & 63;
  const int l31 = lane & 31, hi8 = (lane >> 5) * 8;
  const int mw = (wave >> 1) * 64, nw = (wave & 1) * (TN / 2);
  f32x16 acc[2][CJ];
#pragma unroll
  for (int i = 0; i < 2; ++i)
#pragma unroll
    for (int j = 0; j < CJ; ++j) acc[i][j] = (f32x16)(0.f);

  const int r0 = tid >> 2, c0 = (tid & 3) << 3;
  const bf16* Ap = A + (size_t)(m0 + r0) * K + c0;
  const bf16* Bp = Bt + (size_t)(n0 + r0) * K + c0;
  bf16* lA0 = &As[0][0] + r0 * 32 + c0;
  bf16* lB0 = &Bs[0][0] + r0 * 32 + c0;

#define STAGE_GT(buf, k0)                                                       \
  do {                                                                          \
    bf16* lA = lA0 + (buf) * (2 * 128 * 32);                                    \
    bf16* lB = lB0 + (buf) * (2 * TN * 32);                                     \
    glds16(Ap + (k0), lA);                                                      \
    glds16(Ap + (k0) + (size_t)64 * K, lA + 64 * 32);                           \
    glds16(Ap + (k0) + 32, lA + 128 * 32);                                      \
    glds16(Ap + (k0) + 32 + (size_t)64 * K, lA + 192 * 32);                     \
    glds16(Bp + (k0), lB);                                                      \
    if (TN == 128) glds16(Bp + (k0) + (size_t)64 * K, lB + 64 * 32);            \
    glds16(Bp + (k0) + 32, lB + TN * 32);                                       \
    if (TN == 128) glds16(Bp + (k0) + 32 + (size_t)64 * K, lB + TN * 32 + 64 * 32); \
  } while (0)

#define COMPUTE_GT(buf)                                                          \
  do {                                                                           \
    _Pragma("unroll")                                                            \
    for (int kp = 0; kp < 2; ++kp) {                                             \
      const bf16* Asp = &As[buf][0] + kp * 128 * 32;                             \
      const bf16* Bsp = &Bs[buf][0] + kp * TN * 32;                              \
      _Pragma("unroll")                                                          \
      for (int kh = 0; kh < 2; ++kh) {                                           \
        bf16x8 af[2], bfr[CJ];                                                   \
        _Pragma("unroll")                                                        \
        for (int i = 0; i < 2; ++i)                                              \
          af[i] = *(const bf16x8*)(Asp + (mw + i * 32 + l31) * 32 + kh * 16 + hi8); \
        _Pragma("unroll")                                                        \
        for (int j = 0; j < CJ; ++j)                                             \
          bfr[j] = *(const bf16x8*)(Bsp + (nw + j * 32 + l31) * 32 + kh * 16 + hi8); \
        _Pragma("unroll")                                                        \
        for (int i = 0; i < 2; ++i)                                              \
          _Pragma("unroll")                                                      \
          for (int j = 0; j < CJ; ++j)                                           \
            acc[i][j] = __builtin_amdgcn_mfma_f32_32x32x16_bf16(af[i], bfr[j], acc[i][j], 0, 0, 0); \
      }                                                                          \
    }                                                                            \
  } while (0)

  if (DB == 2) {
    STAGE_GT(0, 0);
    __syncthreads();
    for (int k0 = 0; k0 < K; k0 += 64) {
      const int cur = (k0 >> 6) & 1;
      if (k0 + 64 < K) STAGE_GT(cur ^ 1, k0 + 64);
      COMPUTE_GT(cur);
      __syncthreads();
    }
  } else {
    for (int k0 = 0; k0 < K; k0 += 64) {
      __syncthreads();
      STAGE_GT(0, k0);
      __syncthreads();
      COMPUTE_GT(0);
    }
  }
#undef STAGE_GT
#undef COMPUTE_GT

#pragma unroll
  for (int i = 0; i < 2; ++i) {
    const int rb = m0 + mw + i * 32 + 4 * (lane >> 5);
#pragma unroll
    for (int j = 0; j < CJ; ++j) {
      const int col = n0 + nw + j * 32 + l31;
      const float bv = bias ? bias[col] : 0.f;
#pragma unroll
      for (int reg = 0; reg < 16; ++reg) {
        const int row = rb + (reg & 3) + 8 * (reg >> 2);
        const size_t off = (size_t)row * N + col;
        float v2 = acc[i][j][reg] + bv;
        if (res) v2 += res[off];
        if (Cf) Cf[off] = v2;
        if (Cb) Cb[off] = (bf16)v2;
      }
    }
  }
}

// ---------------- FF1 GEMM + fused GLU (32x32x16 MFMA, N-tile 64) ----------------
__global__ __launch_bounds__(256) void k_gemm_glu(const bf16* __restrict__ A,
                                                  const bf16* __restrict__ Bt,
                                                  const float* __restrict__ bias,
                                                  bf16* __restrict__ Cb,
                                                  int M, int N, int K) {
  __shared__ bf16 As[2 * 128 * 32];
  __shared__ bf16 Ba[2 * 64 * 32];
  __shared__ bf16 Bg[2 * 64 * 32];
  const int m0 = blockIdx.y * 128, n0 = blockIdx.x * 64;
  const int tid = threadIdx.x;
  const int wave = tid >> 6, lane = tid & 63;
  const int l31 = lane & 31, hi8 = (lane >> 5) * 8;
  const int mw = (wave >> 1) * 64, nw = (wave & 1) * 32;
  f32x16 aa[2], ag[2];
#pragma unroll
  for (int i = 0; i < 2; ++i) { aa[i] = (f32x16)(0.f); ag[i] = (f32x16)(0.f); }

  const int r0 = tid >> 2, c0 = (tid & 3) << 3;
  const bf16* Ap = A + (size_t)(m0 + r0) * K + c0;
  const bf16* Bap = Bt + (size_t)(n0 + r0) * K + c0;
  const bf16* Bgp = Bt + (size_t)(N + n0 + r0) * K + c0;
  bf16* lA = As + r0 * 32 + c0;
  bf16* lBa = Ba + r0 * 32 + c0;
  bf16* lBg = Bg + r0 * 32 + c0;

  for (int k0 = 0; k0 < K; k0 += 64) {
    __syncthreads();
    glds16(Ap + k0, lA);
    glds16(Ap + k0 + (size_t)64 * K, lA + 64 * 32);
    glds16(Ap + k0 + 32, lA + 128 * 32);
    glds16(Ap + k0 + 32 + (size_t)64 * K, lA + 192 * 32);
    glds16(Bap + k0, lBa);
    glds16(Bap + k0 + 32, lBa + 64 * 32);
    glds16(Bgp + k0, lBg);
    glds16(Bgp + k0 + 32, lBg + 64 * 32);
    __syncthreads();
#pragma unroll
    for (int kp = 0; kp < 2; ++kp) {
      const bf16* Asp = As + kp * 128 * 32;
      const bf16* Bap_s = Ba + kp * 64 * 32;
      const bf16* Bgp_s = Bg + kp * 64 * 32;
#pragma unroll
      for (int kh = 0; kh < 2; ++kh) {
        bf16x8 af[2], ba, bg;
#pragma unroll
        for (int i = 0; i < 2; ++i)
          af[i] = *(const bf16x8*)(Asp + (mw + i * 32 + l31) * 32 + kh * 16 + hi8);
        ba = *(const bf16x8*)(Bap_s + (nw + l31) * 32 + kh * 16 + hi8);
        bg = *(const bf16x8*)(Bgp_s + (nw + l31) * 32 + kh * 16 + hi8);
#pragma unroll
        for (int i = 0; i < 2; ++i) {
          aa[i] = __builtin_amdgcn_mfma_f32_32x32x16_bf16(af[i], ba, aa[i], 0, 0, 0);
          ag[i] = __builtin_amdgcn_mfma_f32_32x32x16_bf16(af[i], bg, ag[i], 0, 0, 0);
        }
      }
    }
  }

  const int col = n0 + nw + l31;
  const float ba_v = bias[col];
  const float bg_v = bias[N + col];
#pragma unroll
  for (int i = 0; i < 2; ++i) {
    const int rb = m0 + mw + i * 32 + 4 * (lane >> 5);
#pragma unroll
    for (int reg = 0; reg < 16; ++reg) {
      const int row = rb + (reg & 3) + 8 * (reg >> 2);
      float av = aa[i][reg] + ba_v;
      float gv = ag[i][reg] + bg_v;
      float ge = 0.5f * gv * (1.0f + erff(gv * 0.70710678118654752f));
      Cb[(size_t)row * N + col] = (bf16)(av * ge);
    }
  }
}

// ---------------- flash attention, fixed-max softmax, 128 Q-rows/block ----------------
// min-2-phase K/V pipeline: stage(buf^1, next tile) issued BEFORE compute(buf),
// single drain+barrier per kv-tile -> 8KB stage flies under QK/softmax/PV.
__global__ __launch_bounds__(256) void k_attn(const bf16* __restrict__ Qp, int qstride,
                                              const bf16* __restrict__ Kp, int kstride,
                                              const bf16* __restrict__ VTp,
                                              bf16* __restrict__ Op, int kvlen) {
  const int qt = blockIdx.x * 128;
  const int hd = blockIdx.y;
  const int b = blockIdx.z;
  const int tid = threadIdx.x;
  const int wave = tid >> 6, lane = tid & 63;
  const int quad = lane >> 4, l16 = lane & 15;

  __shared__ __align__(16) bf16 Ks[2][64 * 64];
  __shared__ __align__(16) bf16 Vs[2][64 * 64];
  __shared__ __align__(16) bf16 Ps[4][32 * 72];

  bf16x8 qf[2][2];
#pragma unroll
  for (int g = 0; g < 2; ++g) {
    const bf16* qrow = Qp + (size_t)(b * cS + qt + wave * 32 + g * 16 + l16) * qstride + hd * 64;
#pragma unroll
    for (int c = 0; c < 2; ++c) {
      bf16x8 raw = *(const bf16x8*)(qrow + c * 32 + quad * 8);
#pragma unroll
      for (int e = 0; e < 8; ++e) qf[g][c][e] = (bf16)((float)raw[e] * 0.125f);
    }
  }

  float l_part[2][4] = {{0.f, 0.f, 0.f, 0.f}, {0.f, 0.f, 0.f, 0.f}};
  f32x4 o_acc[2][4];
#pragma unroll
  for (int g = 0; g < 2; ++g)
#pragma unroll
    for (int n = 0; n < 4; ++n) o_acc[g][n] = (f32x4){0.f, 0.f, 0.f, 0.f};

  const int lrow = wave * 16 + (lane >> 3);
  const int lcol = (lane & 7) * 8;
  const bf16* kbase = Kp + (size_t)(b * kvlen + lrow) * kstride + hd * 64 + lcol;
  const bf16* vbase = VTp + ((size_t)((b * 16 + hd) * 64 + lrow)) * kvlen + lcol;
  bf16* lk0 = &Ks[0][0] + lrow * 64 + lcol;
  bf16* lv0 = &Vs[0][0] + lrow * 64 + lcol;

#define STAGE_AT(buf, kt)                                              \
  do {                                                                 \
    const bf16* kg = kbase + (size_t)(kt) * kstride;                   \
    bf16* lk = lk0 + (buf) * (64 * 64);                                \
    bf16* lv = lv0 + (buf) * (64 * 64);                                \
    glds16(kg, lk);                                                    \
    glds16(kg + (size_t)8 * kstride, lk + 8 * 64);                     \
    glds16(vbase + (kt), lv);                                          \
    glds16(vbase + (kt) + (size_t)8 * kvlen, lv + 8 * 64);             \
  } while (0)

  STAGE_AT(0, 0);
  __syncthreads();

  for (int kt = 0; kt < kvlen; kt += 64) {
    const int cur = (kt >> 6) & 1;
    if (kt + 64 < kvlen) STAGE_AT(cur ^ 1, kt + 64);

    f32x4 s[2][4];
#pragma unroll
    for (int g = 0; g < 2; ++g)
#pragma unroll
      for (int t = 0; t < 4; ++t) s[g][t] = (f32x4){0.f, 0.f, 0.f, 0.f};
#pragma unroll
    for (int t = 0; t < 4; ++t)
#pragma unroll
      for (int c = 0; c < 2; ++c) {
        bf16x8 kf = *(const bf16x8*)(&Ks[cur][0] + (t * 16 + l16) * 64 + c * 32 + quad * 8);
#pragma unroll
        for (int g = 0; g < 2; ++g)
          s[g][t] = __builtin_amdgcn_mfma_f32_16x16x32_bf16(qf[g][c], kf, s[g][t], 0, 0, 0);
      }

#pragma unroll
    for (int g = 0; g < 2; ++g)
#pragma unroll
      for (int t = 0; t < 4; ++t)
#pragma unroll
        for (int r = 0; r < 4; ++r) {
          float p = __expf(s[g][t][r]);
          Ps[wave][(g * 16 + quad * 4 + r) * 72 + t * 16 + l16] = (bf16)p;
          l_part[g][r] += p;
        }

    bf16x8 pf[2][2];
#pragma unroll
    for (int g = 0; g < 2; ++g)
#pragma unroll
      for (int c = 0; c < 2; ++c)
        pf[g][c] = *(const bf16x8*)(&Ps[wave][(g * 16 + l16) * 72 + c * 32 + quad * 8]);
#pragma unroll
    for (int n = 0; n < 4; ++n)
#pragma unroll
      for (int c = 0; c < 2; ++c) {
        bf16x8 vf = *(const bf16x8*)(&Vs[cur][0] + (n * 16 + l16) * 64 + c * 32 + quad * 8);
#pragma unroll
        for (int g = 0; g < 2; ++g)
          o_acc[g][n] = __builtin_amdgcn_mfma_f32_16x16x32_bf16(pf[g][c], vf, o_acc[g][n], 0, 0, 0);
      }
    __syncthreads();
  }
#undef STAGE_AT

#pragma unroll
  for (int g = 0; g < 2; ++g) {
    float rl[4];
#pragma unroll
    for (int r = 0; r < 4; ++r) {
      float v = l_part[g][r];
      v += __shfl_xor(v, 1);
      v += __shfl_xor(v, 2);
      v += __shfl_xor(v, 4);
      v += __shfl_xor(v, 8);
      rl[r] = 1.f / v;
    }
#pragma unroll
    for (int n = 0; n < 4; ++n)
#pragma unroll
      for (int r = 0; r < 4; ++r) {
        const int srow = qt + wave * 32 + g * 16 + quad * 4 + r;
        const int d = n * 16 + l16;
        Op[(size_t)(b * cS + srow) * 1024 + hd * 64 + d] = (bf16)(o_acc[g][n][r] * rl[r]);
      }
  }
}

// ---------------- launch ----------------
extern "C" void kernel_launch(void* const* d_in, const int* in_sizes, int n_in,
                              void* d_out, int out_size, void* d_ws, size_t ws_size,
                              hipStream_t stream) {
  const float* x    = (const float*)d_in[0];
  const float* tt   = (const float*)d_in[1];
  const float* ctx  = (const float*)d_in[2];
  const float* fw1  = (const float*)d_in[13];
  const float* fb1  = (const float*)d_in[14];
  const float* fw2  = (const float*)d_in[15];
  const float* fb2  = (const float*)d_in[16];
  const float* a1bo = (const float*)d_in[7];
  const float* a2bo = (const float*)d_in[12];

  char* ws = (char*)d_ws;
  const size_t MB = 1ull << 20;
  // 8 square transposed weights packed: [q1,k1,v1,o1,q2,k2,v2,o2] x 2 MB
  bf16* wsq   = (bf16*)(ws + 0 * MB);
  bf16* wqkv1 = wsq;                               // mats 0-2
  bf16* wto1  = (bf16*)(ws + 6 * MB);              // mat 3
  bf16* wtq2  = (bf16*)(ws + 8 * MB);              // mat 4
  bf16* wkv2w = (bf16*)(ws + 10 * MB);             // mats 5-6
  bf16* wto2  = (bf16*)(ws + 14 * MB);             // mat 7
  bf16* wtf1  = (bf16*)(ws + 16 * MB);             // [8192,1024], 16 MB
  bf16* wtf2  = (bf16*)(ws + 32 * MB);             // [1024,4096], 8 MB
  float* emb  = (float*)(ws + 40 * MB);            // 3 x [2,2048]
  float* emb1 = emb, *emb2 = emb + 4096, *emb3 = emb + 8192;
  bf16* ctxb  = (bf16*)(ws + 40 * MB + 262144);    // [512,1024], 1 MB
  float* xres = (float*)(ws + 42 * MB);            // fp32 residual, 16 MB
  bf16* h     = (bf16*)(ws + 58 * MB);             // 8 MB
  bf16* ao    = h;
  bf16* qkv   = (bf16*)(ws + 66 * MB);             // [4096,3072], 24 MB
  bf16* q2    = qkv;
  bf16* vT1   = (bf16*)(ws + 90 * MB);             // [32*64,2048], 8 MB
  bf16* kv2   = (bf16*)(ws + 0 * MB);              // [512,2048], 2 MB (aliases dead mats 0-1)
  bf16* vT2   = (bf16*)(ws + 2 * MB);              // [32*64,256], 1 MB (aliases dead mat 1)
  bf16* g     = (bf16*)(ws + 66 * MB);             // [4096,4096], 32 MB
  float* out  = (float*)d_out;

  const dim3 blk(256);

  T8 t8;
  t8.s[0] = (const float*)d_in[3];   // a1wq
  t8.s[1] = (const float*)d_in[4];   // a1wk
  t8.s[2] = (const float*)d_in[5];   // a1wv
  t8.s[3] = (const float*)d_in[6];   // a1wo
  t8.s[4] = (const float*)d_in[8];   // a2wq
  t8.s[5] = (const float*)d_in[9];   // a2wk
  t8.s[6] = (const float*)d_in[10];  // a2wv
  t8.s[7] = (const float*)d_in[11];  // a2wo
  k_transpose8<<<dim3(16, 16, 8), blk, 0, stream>>>(t8, wsq);
  k_transpose<<<dim3(128, 16), blk, 0, stream>>>(fw1, wtf1, 1024, 8192);
  k_transpose<<<dim3(16, 64), blk, 0, stream>>>(fw2, wtf2, 4096, 1024);

  EmbArgs ea;
  ea.w0 = (const float*)d_in[17]; ea.b0 = (const float*)d_in[18];
  ea.w1 = (const float*)d_in[19]; ea.b1 = (const float*)d_in[20];
  ea.w2 = (const float*)d_in[21]; ea.b2 = (const float*)d_in[22];
  k_emb3<<<dim3(32, 3), blk, 0, stream>>>(tt, ea, emb);
  k_f2b<<<512, blk, 0, stream>>>(ctx, ctxb);

  // ---- block 1: self-attention ----
  k_adaln<<<4096, blk, 0, stream>>>(x, emb1, h);
  k_gemm_t<128, 1><<<dim3(24, 32), blk, 0, stream>>>(h, wqkv1, qkv, nullptr, nullptr, nullptr, 4096, 3072, 1024);
  k_vt<<<dim3(32, 32), blk, 0, stream>>>(qkv + 2048, 3072, vT1, 2048);
  k_attn<<<dim3(16, 16, 2), blk, 0, stream>>>(qkv, 3072, qkv + 1024, 3072, vT1, ao, 2048);
  k_gemm_t<64, 2><<<dim3(16, 32), blk, 0, stream>>>(ao, wto1, nullptr, xres, a1bo, x, 4096, 1024, 1024);

  // ---- block 2: cross-attention ----
  k_adaln<<<4096, blk, 0, stream>>>(xres, emb2, h);
  k_gemm_t<64, 2><<<dim3(16, 32), blk, 0, stream>>>(h, wtq2, q2, nullptr, nullptr, nullptr, 4096, 1024, 1024);
  k_gemm_t<128, 1><<<dim3(16, 4), blk, 0, stream>>>(ctxb, wkv2w, kv2, nullptr, nullptr, nullptr, 512, 2048, 1024);
  k_vt<<<dim3(4, 32), blk, 0, stream>>>(kv2 + 1024, 2048, vT2, 256);
  k_attn<<<dim3(16, 16, 2), blk, 0, stream>>>(q2, 1024, kv2, 2048, vT2, ao, 256);
  k_gemm_t<64, 2><<<dim3(16, 32), blk, 0, stream>>>(ao, wto2, nullptr, xres, a2bo, xres, 4096, 1024, 1024);

  // ---- block 3: gated-GELU FFN ----
  k_adaln<<<4096, blk, 0, stream>>>(xres, emb3, h);
  k_gemm_glu<<<dim3(64, 32), blk, 0, stream>>>(h, wtf1, fb1, g, 4096, 4096, 1024);
  k_gemm_t<64, 2><<<dim3(16, 32), blk, 0, stream>>>(g, wtf2, nullptr, out, fb2, xres, 4096, 1024, 4096);
}

// Round 5
// 617.622 us; speedup vs baseline: 1.0396x; 1.0122x over previous
//
#include <hip/hip_runtime.h>
#include <hip/hip_bf16.h>
#include <math.h>
#include <stdint.h>

typedef __bf16 bf16;
typedef __attribute__((ext_vector_type(8))) __bf16 bf16x8;
typedef __attribute__((ext_vector_type(4))) __bf16 bf16x4;
typedef __attribute__((ext_vector_type(4))) float f32x4;
typedef __attribute__((ext_vector_type(16))) float f32x16;

static constexpr int cB = 2, cS = 2048, cCTX = 256, cD = 1024, cH = 16, cDH = 64, cDFF = 4096;

// async 16B global->LDS. HW semantics: dest = wave-uniform base + lane*16.
// Every call site MUST have lane i's lds ptr == base + 16*i bytes.
__device__ __forceinline__ void glds16(const bf16* g, bf16* l) {
  __builtin_amdgcn_global_load_lds(
      (const __attribute__((address_space(1))) void*)g,
      (__attribute__((address_space(3))) void*)l, 16, 0, 0);
}

// ---------------- batched transpose+convert: 8x fp32 [1024,1024] -> bf16 [1024,1024]^T ----------------
struct T8 { const float* s[8]; };
__global__ __launch_bounds__(256) void k_transpose8(T8 args, bf16* __restrict__ out) {
  __shared__ bf16 tile[64][66];
  const int n0 = blockIdx.x * 64, k0 = blockIdx.y * 64;
  const int z = blockIdx.z;
  const float* in = args.s[z];
  bf16* dst_base = out + (size_t)z * 1024 * 1024;
  const int t = threadIdx.x;
  const int r = t >> 2, cb = (t & 3) * 16;
  const float* src = in + (size_t)(k0 + r) * 1024 + n0 + cb;
#pragma unroll
  for (int q4 = 0; q4 < 4; ++q4) {
    f32x4 v = *(const f32x4*)(src + q4 * 4);
#pragma unroll
    for (int e = 0; e < 4; ++e) tile[r][cb + q4 * 4 + e] = (bf16)v[e];
  }
  __syncthreads();
  bf16* dst = dst_base + (size_t)(n0 + r) * 1024 + k0 + cb;
  bf16x8 o0, o1;
#pragma unroll
  for (int e = 0; e < 8; ++e) { o0[e] = tile[cb + e][r]; o1[e] = tile[cb + 8 + e][r]; }
  *(bf16x8*)(dst) = o0;
  *(bf16x8*)(dst + 8) = o1;
}

// ---------------- transpose+convert: fp32 [K,N] -> bf16 [N,K] (for ff weights) ----------------
__global__ __launch_bounds__(256) void k_transpose(const float* __restrict__ in,
                                                   bf16* __restrict__ out, int K, int N) {
  __shared__ bf16 tile[64][66];
  const int n0 = blockIdx.x * 64, k0 = blockIdx.y * 64;
  const int t = threadIdx.x;
  const int r = t >> 2, cb = (t & 3) * 16;
  const float* src = in + (size_t)(k0 + r) * N + n0 + cb;
#pragma unroll
  for (int q4 = 0; q4 < 4; ++q4) {
    f32x4 v = *(const f32x4*)(src + q4 * 4);
#pragma unroll
    for (int e = 0; e < 4; ++e) tile[r][cb + q4 * 4 + e] = (bf16)v[e];
  }
  __syncthreads();
  bf16* dst = out + (size_t)(n0 + r) * K + k0 + cb;
  bf16x8 o0, o1;
#pragma unroll
  for (int e = 0; e < 8; ++e) { o0[e] = tile[cb + e][r]; o1[e] = tile[cb + 8 + e][r]; }
  *(bf16x8*)(dst) = o0;
  *(bf16x8*)(dst + 8) = o1;
}

// ---------------- V transpose -> VT[(b*16+h)*64+d][kvlen] ----------------
__global__ __launch_bounds__(256) void k_vt(const bf16* __restrict__ V, int vstride,
                                            bf16* __restrict__ VT, int kvlen) {
  __shared__ bf16 tile[64][72];
  const int kt = blockIdx.x * 64, bh = blockIdx.y;
  const int b = bh >> 4, h = bh & 15;
  const int t = threadIdx.x, r = t >> 2, cb = (t & 3) * 16;
  const bf16* src = V + (size_t)(b * kvlen + kt + r) * vstride + h * 64 + cb;
  bf16x8 a0 = *(const bf16x8*)src;
  bf16x8 a1 = *(const bf16x8*)(src + 8);
#pragma unroll
  for (int e = 0; e < 8; ++e) { tile[r][cb + e] = a0[e]; tile[r][cb + 8 + e] = a1[e]; }
  __syncthreads();
  bf16* dst = VT + ((size_t)bh * 64 + r) * kvlen + kt + cb;
  bf16x8 o0, o1;
#pragma unroll
  for (int e = 0; e < 8; ++e) { o0[e] = tile[cb + e][r]; o1[e] = tile[cb + 8 + e][r]; }
  *(bf16x8*)(dst) = o0;
  *(bf16x8*)(dst + 8) = o1;
}

// ---------------- fp32 -> bf16 elementwise ----------------
__global__ __launch_bounds__(256) void k_f2b(const float* __restrict__ in, bf16* __restrict__ out) {
  const int base = (blockIdx.x * 256 + threadIdx.x) * 4;
  f32x4 v = *(const f32x4*)(in + base);
  bf16x4 o;
#pragma unroll
  for (int e = 0; e < 4; ++e) o[e] = (bf16)v[e];
  *(bf16x4*)(out + base) = o;
}

// ---------------- merged emb: emb_i = t @ W_i + b_i -> fp32 [3][2,2048] ----------------
struct EmbArgs { const float* w0; const float* w1; const float* w2;
                 const float* b0; const float* b1; const float* b2; };
__global__ __launch_bounds__(256) void k_emb3(const float* __restrict__ t, EmbArgs ea,
                                              float* __restrict__ emb) {
  const int which = blockIdx.y;
  const float* w = which == 0 ? ea.w0 : (which == 1 ? ea.w1 : ea.w2);
  const float* bias = which == 0 ? ea.b0 : (which == 1 ? ea.b1 : ea.b2);
  float* dst = emb + which * 4096;
  const int jj = threadIdx.x & 63;
  const int j = blockIdx.x * 64 + jj;
  const int kg = threadIdx.x >> 6;
  float a0 = 0.f, a1 = 0.f;
  for (int k = kg * 256; k < kg * 256 + 256; ++k) {
    float wv = w[(size_t)k * 2048 + j];
    a0 += t[k] * wv;
    a1 += t[1024 + k] * wv;
  }
  __shared__ float s0[4][64], s1[4][64];
  s0[kg][jj] = a0;
  s1[kg][jj] = a1;
  __syncthreads();
  if (threadIdx.x < 64) {
    dst[j] = s0[0][jj] + s0[1][jj] + s0[2][jj] + s0[3][jj] + bias[j];
    dst[2048 + j] = s1[0][jj] + s1[1][jj] + s1[2][jj] + s1[3][jj] + bias[j];
  }
}

// ---------------- AdaLN ----------------
__global__ __launch_bounds__(256) void k_adaln(const float* __restrict__ xres,
                                               const float* __restrict__ emb,
                                               bf16* __restrict__ h) {
  const int token = blockIdx.x;
  const int b = token >> 11;
  const float* x = xres + (size_t)token * 1024;
  const float* sc = emb + b * 2048;
  const int t = threadIdx.x;
  float v[4], s = 0.f, sq = 0.f;
#pragma unroll
  for (int i = 0; i < 4; ++i) {
    float u = x[t + 256 * i];
    v[i] = u; s += u; sq += u * u;
  }
#pragma unroll
  for (int off = 1; off < 64; off <<= 1) {
    s += __shfl_xor(s, off);
    sq += __shfl_xor(sq, off);
  }
  __shared__ float ss[4], ssq[4];
  const int wave = t >> 6;
  if ((t & 63) == 0) { ss[wave] = s; ssq[wave] = sq; }
  __syncthreads();
  const float S_ = ss[0] + ss[1] + ss[2] + ss[3];
  const float SQ = ssq[0] + ssq[1] + ssq[2] + ssq[3];
  const float mean = S_ * (1.f / 1024.f);
  const float var = SQ * (1.f / 1024.f) - mean * mean;
  const float rstd = rsqrtf(var + 1e-5f);
#pragma unroll
  for (int i = 0; i < 4; ++i) {
    const int c = t + 256 * i;
    float val = (v[i] - mean) * rstd * (1.f + sc[c]) + sc[1024 + c];
    h[(size_t)token * 1024 + c] = (bf16)val;
  }
}

// ---------------- GEMM (32x32x16 MFMA): C[M,N] = A[M,K] @ Bt[N,K]^T (+bias)(+res) ----------------
// DB=1: original 2-barrier structure (for TN=128 sites at 3+ blocks/CU).
// DB=2: minimum-2-phase (T3 minimum): stage(buf^1) issued BEFORE compute(buf),
//       one vmcnt(0)+barrier per K-step -> staged loads fly under the MFMA.
template <int TN, int DB>
__global__ __launch_bounds__(256) void k_gemm_t(const bf16* __restrict__ A,
                                                const bf16* __restrict__ Bt,
                                                bf16* Cb, float* Cf,
                                                const float* __restrict__ bias,
                                                const float* res,
                                                int M, int N, int K) {
  constexpr int CJ = TN / 64;  // 32-col MFMA tiles per wave (1 or 2)
  __shared__ bf16 As[DB][2 * 128 * 32];
  __shared__ bf16 Bs[DB][2 * TN * 32];
  const int m0 = blockIdx.y * 128, n0 = blockIdx.x * TN;
  const int tid = threadIdx.x;
  const int wave = tid >> 6, lane = tid & 63;
  const int l31 = lane & 31, hi8 = (lane >> 5) * 8;
  const int mw = (wave >> 1) * 64, nw = (wave & 1) * (TN / 2);
  f32x16 acc[2][CJ];
#pragma unroll
  for (int i = 0; i < 2; ++i)
#pragma unroll
    for (int j = 0; j < CJ; ++j) acc[i][j] = (f32x16)(0.f);

  const int r0 = tid >> 2, c0 = (tid & 3) << 3;
  const bf16* Ap = A + (size_t)(m0 + r0) * K + c0;
  const bf16* Bp = Bt + (size_t)(n0 + r0) * K + c0;
  bf16* lA0 = &As[0][0] + r0 * 32 + c0;
  bf16* lB0 = &Bs[0][0] + r0 * 32 + c0;

#define STAGE_GT(buf, k0)                                                       \
  do {                                                                          \
    bf16* lA = lA0 + (buf) * (2 * 128 * 32);                                    \
    bf16* lB = lB0 + (buf) * (2 * TN * 32);                                     \
    glds16(Ap + (k0), lA);                                                      \
    glds16(Ap + (k0) + (size_t)64 * K, lA + 64 * 32);                           \
    glds16(Ap + (k0) + 32, lA + 128 * 32);                                      \
    glds16(Ap + (k0) + 32 + (size_t)64 * K, lA + 192 * 32);                     \
    glds16(Bp + (k0), lB);                                                      \
    if (TN == 128) glds16(Bp + (k0) + (size_t)64 * K, lB + 64 * 32);            \
    glds16(Bp + (k0) + 32, lB + TN * 32);                                       \
    if (TN == 128) glds16(Bp + (k0) + 32 + (size_t)64 * K, lB + TN * 32 + 64 * 32); \
  } while (0)

#define COMPUTE_GT(buf)                                                          \
  do {                                                                           \
    _Pragma("unroll")                                                            \
    for (int kp = 0; kp < 2; ++kp) {                                             \
      const bf16* Asp = &As[buf][0] + kp * 128 * 32;                             \
      const bf16* Bsp = &Bs[buf][0] + kp * TN * 32;                              \
      _Pragma("unroll")                                                          \
      for (int kh = 0; kh < 2; ++kh) {                                           \
        bf16x8 af[2], bfr[CJ];                                                   \
        _Pragma("unroll")                                                        \
        for (int i = 0; i < 2; ++i)                                              \
          af[i] = *(const bf16x8*)(Asp + (mw + i * 32 + l31) * 32 + kh * 16 + hi8); \
        _Pragma("unroll")                                                        \
        for (int j = 0; j < CJ; ++j)                                             \
          bfr[j] = *(const bf16x8*)(Bsp + (nw + j * 32 + l31) * 32 + kh * 16 + hi8); \
        _Pragma("unroll")                                                        \
        for (int i = 0; i < 2; ++i)                                              \
          _Pragma("unroll")                                                      \
          for (int j = 0; j < CJ; ++j)                                           \
            acc[i][j] = __builtin_amdgcn_mfma_f32_32x32x16_bf16(af[i], bfr[j], acc[i][j], 0, 0, 0); \
      }                                                                          \
    }                                                                            \
  } while (0)

  if (DB == 2) {
    STAGE_GT(0, 0);
    __syncthreads();
    for (int k0 = 0; k0 < K; k0 += 64) {
      const int cur = (k0 >> 6) & 1;
      if (k0 + 64 < K) STAGE_GT(cur ^ 1, k0 + 64);
      COMPUTE_GT(cur);
      __syncthreads();
    }
  } else {
    for (int k0 = 0; k0 < K; k0 += 64) {
      __syncthreads();
      STAGE_GT(0, k0);
      __syncthreads();
      COMPUTE_GT(0);
    }
  }
#undef STAGE_GT
#undef COMPUTE_GT

#pragma unroll
  for (int i = 0; i < 2; ++i) {
    const int rb = m0 + mw + i * 32 + 4 * (lane >> 5);
#pragma unroll
    for (int j = 0; j < CJ; ++j) {
      const int col = n0 + nw + j * 32 + l31;
      const float bv = bias ? bias[col] : 0.f;
#pragma unroll
      for (int reg = 0; reg < 16; ++reg) {
        const int row = rb + (reg & 3) + 8 * (reg >> 2);
        const size_t off = (size_t)row * N + col;
        float v2 = acc[i][j][reg] + bv;
        if (res) v2 += res[off];
        if (Cf) Cf[off] = v2;
        if (Cb) Cb[off] = (bf16)v2;
      }
    }
  }
}

// ---------------- FF1 GEMM + fused GLU (32x32x16 MFMA, N-tile 64) ----------------
__global__ __launch_bounds__(256) void k_gemm_glu(const bf16* __restrict__ A,
                                                  const bf16* __restrict__ Bt,
                                                  const float* __restrict__ bias,
                                                  bf16* __restrict__ Cb,
                                                  int M, int N, int K) {
  __shared__ bf16 As[2 * 128 * 32];
  __shared__ bf16 Ba[2 * 64 * 32];
  __shared__ bf16 Bg[2 * 64 * 32];
  const int m0 = blockIdx.y * 128, n0 = blockIdx.x * 64;
  const int tid = threadIdx.x;
  const int wave = tid >> 6, lane = tid & 63;
  const int l31 = lane & 31, hi8 = (lane >> 5) * 8;
  const int mw = (wave >> 1) * 64, nw = (wave & 1) * 32;
  f32x16 aa[2], ag[2];
#pragma unroll
  for (int i = 0; i < 2; ++i) { aa[i] = (f32x16)(0.f); ag[i] = (f32x16)(0.f); }

  const int r0 = tid >> 2, c0 = (tid & 3) << 3;
  const bf16* Ap = A + (size_t)(m0 + r0) * K + c0;
  const bf16* Bap = Bt + (size_t)(n0 + r0) * K + c0;
  const bf16* Bgp = Bt + (size_t)(N + n0 + r0) * K + c0;
  bf16* lA = As + r0 * 32 + c0;
  bf16* lBa = Ba + r0 * 32 + c0;
  bf16* lBg = Bg + r0 * 32 + c0;

  for (int k0 = 0; k0 < K; k0 += 64) {
    __syncthreads();
    glds16(Ap + k0, lA);
    glds16(Ap + k0 + (size_t)64 * K, lA + 64 * 32);
    glds16(Ap + k0 + 32, lA + 128 * 32);
    glds16(Ap + k0 + 32 + (size_t)64 * K, lA + 192 * 32);
    glds16(Bap + k0, lBa);
    glds16(Bap + k0 + 32, lBa + 64 * 32);
    glds16(Bgp + k0, lBg);
    glds16(Bgp + k0 + 32, lBg + 64 * 32);
    __syncthreads();
#pragma unroll
    for (int kp = 0; kp < 2; ++kp) {
      const bf16* Asp = As + kp * 128 * 32;
      const bf16* Bap_s = Ba + kp * 64 * 32;
      const bf16* Bgp_s = Bg + kp * 64 * 32;
#pragma unroll
      for (int kh = 0; kh < 2; ++kh) {
        bf16x8 af[2], ba, bg;
#pragma unroll
        for (int i = 0; i < 2; ++i)
          af[i] = *(const bf16x8*)(Asp + (mw + i * 32 + l31) * 32 + kh * 16 + hi8);
        ba = *(const bf16x8*)(Bap_s + (nw + l31) * 32 + kh * 16 + hi8);
        bg = *(const bf16x8*)(Bgp_s + (nw + l31) * 32 + kh * 16 + hi8);
#pragma unroll
        for (int i = 0; i < 2; ++i) {
          aa[i] = __builtin_amdgcn_mfma_f32_32x32x16_bf16(af[i], ba, aa[i], 0, 0, 0);
          ag[i] = __builtin_amdgcn_mfma_f32_32x32x16_bf16(af[i], bg, ag[i], 0, 0, 0);
        }
      }
    }
  }

  const int col = n0 + nw + l31;
  const float ba_v = bias[col];
  const float bg_v = bias[N + col];
#pragma unroll
  for (int i = 0; i < 2; ++i) {
    const int rb = m0 + mw + i * 32 + 4 * (lane >> 5);
#pragma unroll
    for (int reg = 0; reg < 16; ++reg) {
      const int row = rb + (reg & 3) + 8 * (reg >> 2);
      float av = aa[i][reg] + ba_v;
      float gv = ag[i][reg] + bg_v;
      float ge = 0.5f * gv * (1.0f + erff(gv * 0.70710678118654752f));
      Cb[(size_t)row * N + col] = (bf16)(av * ge);
    }
  }
}

// ---------------- flash attention, fixed-max softmax, 128 Q-rows/block ----------------
// min-2-phase K/V pipeline + XOR-swizzled K/V tiles.
// Swizzle (rule #21): linear LDS dest; global SOURCE chunk = c ^ (row&7);
// read physical chunk = logical ^ (row&7). [64][64el] rows are 128B, so the
// unswizzled ds_read_b128 was a 16-way bank conflict (each 16-lane group hits
// the same 4 banks); post-swizzle 2 lanes/chunk across all 32 banks = free.
__global__ __launch_bounds__(256) void k_attn(const bf16* __restrict__ Qp, int qstride,
                                              const bf16* __restrict__ Kp, int kstride,
                                              const bf16* __restrict__ VTp,
                                              bf16* __restrict__ Op, int kvlen) {
  const int qt = blockIdx.x * 128;
  const int hd = blockIdx.y;
  const int b = blockIdx.z;
  const int tid = threadIdx.x;
  const int wave = tid >> 6, lane = tid & 63;
  const int quad = lane >> 4, l16 = lane & 15;
  const int rswq = l16 & 7;                  // read-side chunk XOR (row&7 of read row)

  __shared__ __align__(16) bf16 Ks[2][64 * 64];
  __shared__ __align__(16) bf16 Vs[2][64 * 64];
  __shared__ __align__(16) bf16 Ps[4][32 * 72];

  bf16x8 qf[2][2];
#pragma unroll
  for (int g = 0; g < 2; ++g) {
    const bf16* qrow = Qp + (size_t)(b * cS + qt + wave * 32 + g * 16 + l16) * qstride + hd * 64;
#pragma unroll
    for (int c = 0; c < 2; ++c) {
      bf16x8 raw = *(const bf16x8*)(qrow + c * 32 + quad * 8);
#pragma unroll
      for (int e = 0; e < 8; ++e) qf[g][c][e] = (bf16)((float)raw[e] * 0.125f);
    }
  }

  float l_part[2][4] = {{0.f, 0.f, 0.f, 0.f}, {0.f, 0.f, 0.f, 0.f}};
  f32x4 o_acc[2][4];
#pragma unroll
  for (int g = 0; g < 2; ++g)
#pragma unroll
    for (int n = 0; n < 4; ++n) o_acc[g][n] = (f32x4){0.f, 0.f, 0.f, 0.f};

  const int lrow = wave * 16 + (lane >> 3);                // staged row (row&7 = (lane>>3)&7)
  const int lcol = (lane & 7) * 8;                         // linear LDS dest chunk
  const int scol = (((lane & 7) ^ ((lane >> 3) & 7)) * 8); // inverse-swizzled global src
  const bf16* kbase = Kp + (size_t)(b * kvlen + lrow) * kstride + hd * 64 + scol;
  const bf16* vbase = VTp + ((size_t)((b * 16 + hd) * 64 + lrow)) * kvlen + scol;
  bf16* lk0 = &Ks[0][0] + lrow * 64 + lcol;
  bf16* lv0 = &Vs[0][0] + lrow * 64 + lcol;

#define STAGE_AT(buf, kt)                                              \
  do {                                                                 \
    const bf16* kg = kbase + (size_t)(kt) * kstride;                   \
    bf16* lk = lk0 + (buf) * (64 * 64);                                \
    bf16* lv = lv0 + (buf) * (64 * 64);                                \
    glds16(kg, lk);                                                    \
    glds16(kg + (size_t)8 * kstride, lk + 8 * 64);                     \
    glds16(vbase + (kt), lv);                                          \
    glds16(vbase + (kt) + (size_t)8 * kvlen, lv + 8 * 64);             \
  } while (0)

  STAGE_AT(0, 0);
  __syncthreads();

  for (int kt = 0; kt < kvlen; kt += 64) {
    const int cur = (kt >> 6) & 1;
    if (kt + 64 < kvlen) STAGE_AT(cur ^ 1, kt + 64);

    f32x4 s[2][4];
#pragma unroll
    for (int g = 0; g < 2; ++g)
#pragma unroll
      for (int t = 0; t < 4; ++t) s[g][t] = (f32x4){0.f, 0.f, 0.f, 0.f};
#pragma unroll
    for (int t = 0; t < 4; ++t)
#pragma unroll
      for (int c = 0; c < 2; ++c) {
        bf16x8 kf = *(const bf16x8*)(&Ks[cur][0] + (t * 16 + l16) * 64 + (((c * 4 + quad) ^ rswq) << 3));
#pragma unroll
        for (int g = 0; g < 2; ++g)
          s[g][t] = __builtin_amdgcn_mfma_f32_16x16x32_bf16(qf[g][c], kf, s[g][t], 0, 0, 0);
      }

#pragma unroll
    for (int g = 0; g < 2; ++g)
#pragma unroll
      for (int t = 0; t < 4; ++t)
#pragma unroll
        for (int r = 0; r < 4; ++r) {
          float p = __expf(s[g][t][r]);
          Ps[wave][(g * 16 + quad * 4 + r) * 72 + t * 16 + l16] = (bf16)p;
          l_part[g][r] += p;
        }

    bf16x8 pf[2][2];
#pragma unroll
    for (int g = 0; g < 2; ++g)
#pragma unroll
      for (int c = 0; c < 2; ++c)
        pf[g][c] = *(const bf16x8*)(&Ps[wave][(g * 16 + l16) * 72 + c * 32 + quad * 8]);
#pragma unroll
    for (int n = 0; n < 4; ++n)
#pragma unroll
      for (int c = 0; c < 2; ++c) {
        bf16x8 vf = *(const bf16x8*)(&Vs[cur][0] + (n * 16 + l16) * 64 + (((c * 4 + quad) ^ rswq) << 3));
#pragma unroll
        for (int g = 0; g < 2; ++g)
          o_acc[g][n] = __builtin_amdgcn_mfma_f32_16x16x32_bf16(pf[g][c], vf, o_acc[g][n], 0, 0, 0);
      }
    __syncthreads();
  }
#undef STAGE_AT

#pragma unroll
  for (int g = 0; g < 2; ++g) {
    float rl[4];
#pragma unroll
    for (int r = 0; r < 4; ++r) {
      float v = l_part[g][r];
      v += __shfl_xor(v, 1);
      v += __shfl_xor(v, 2);
      v += __shfl_xor(v, 4);
      v += __shfl_xor(v, 8);
      rl[r] = 1.f / v;
    }
#pragma unroll
    for (int n = 0; n < 4; ++n)
#pragma unroll
      for (int r = 0; r < 4; ++r) {
        const int srow = qt + wave * 32 + g * 16 + quad * 4 + r;
        const int d = n * 16 + l16;
        Op[(size_t)(b * cS + srow) * 1024 + hd * 64 + d] = (bf16)(o_acc[g][n][r] * rl[r]);
      }
  }
}

// ---------------- launch ----------------
extern "C" void kernel_launch(void* const* d_in, const int* in_sizes, int n_in,
                              void* d_out, int out_size, void* d_ws, size_t ws_size,
                              hipStream_t stream) {
  const float* x    = (const float*)d_in[0];
  const float* tt   = (const float*)d_in[1];
  const float* ctx  = (const float*)d_in[2];
  const float* fw1  = (const float*)d_in[13];
  const float* fb1  = (const float*)d_in[14];
  const float* fw2  = (const float*)d_in[15];
  const float* fb2  = (const float*)d_in[16];
  const float* a1bo = (const float*)d_in[7];
  const float* a2bo = (const float*)d_in[12];

  char* ws = (char*)d_ws;
  const size_t MB = 1ull << 20;
  // 8 square transposed weights packed: [q1,k1,v1,o1,q2,k2,v2,o2] x 2 MB
  bf16* wsq   = (bf16*)(ws + 0 * MB);
  bf16* wqkv1 = wsq;                               // mats 0-2
  bf16* wto1  = (bf16*)(ws + 6 * MB);              // mat 3
  bf16* wtq2  = (bf16*)(ws + 8 * MB);              // mat 4
  bf16* wkv2w = (bf16*)(ws + 10 * MB);             // mats 5-6
  bf16* wto2  = (bf16*)(ws + 14 * MB);             // mat 7
  bf16* wtf1  = (bf16*)(ws + 16 * MB);             // [8192,1024], 16 MB
  bf16* wtf2  = (bf16*)(ws + 32 * MB);             // [1024,4096], 8 MB
  float* emb  = (float*)(ws + 40 * MB);            // 3 x [2,2048]
  float* emb1 = emb, *emb2 = emb + 4096, *emb3 = emb + 8192;
  bf16* ctxb  = (bf16*)(ws + 40 * MB + 262144);    // [512,1024], 1 MB
  float* xres = (float*)(ws + 42 * MB);            // fp32 residual, 16 MB
  bf16* h     = (bf16*)(ws + 58 * MB);             // 8 MB
  bf16* ao    = h;
  bf16* qkv   = (bf16*)(ws + 66 * MB);             // [4096,3072], 24 MB
  bf16* q2    = qkv;
  bf16* vT1   = (bf16*)(ws + 90 * MB);             // [32*64,2048], 8 MB
  bf16* kv2   = (bf16*)(ws + 0 * MB);              // [512,2048], 2 MB (aliases dead mats 0-1)
  bf16* vT2   = (bf16*)(ws + 2 * MB);              // [32*64,256], 1 MB (aliases dead mat 1)
  bf16* g     = (bf16*)(ws + 66 * MB);             // [4096,4096], 32 MB
  float* out  = (float*)d_out;

  const dim3 blk(256);

  T8 t8;
  t8.s[0] = (const float*)d_in[3];   // a1wq
  t8.s[1] = (const float*)d_in[4];   // a1wk
  t8.s[2] = (const float*)d_in[5];   // a1wv
  t8.s[3] = (const float*)d_in[6];   // a1wo
  t8.s[4] = (const float*)d_in[8];   // a2wq
  t8.s[5] = (const float*)d_in[9];   // a2wk
  t8.s[6] = (const float*)d_in[10];  // a2wv
  t8.s[7] = (const float*)d_in[11];  // a2wo
  k_transpose8<<<dim3(16, 16, 8), blk, 0, stream>>>(t8, wsq);
  k_transpose<<<dim3(128, 16), blk, 0, stream>>>(fw1, wtf1, 1024, 8192);
  k_transpose<<<dim3(16, 64), blk, 0, stream>>>(fw2, wtf2, 4096, 1024);

  EmbArgs ea;
  ea.w0 = (const float*)d_in[17]; ea.b0 = (const float*)d_in[18];
  ea.w1 = (const float*)d_in[19]; ea.b1 = (const float*)d_in[20];
  ea.w2 = (const float*)d_in[21]; ea.b2 = (const float*)d_in[22];
  k_emb3<<<dim3(32, 3), blk, 0, stream>>>(tt, ea, emb);
  k_f2b<<<512, blk, 0, stream>>>(ctx, ctxb);

  // ---- block 1: self-attention ----
  k_adaln<<<4096, blk, 0, stream>>>(x, emb1, h);
  k_gemm_t<128, 1><<<dim3(24, 32), blk, 0, stream>>>(h, wqkv1, qkv, nullptr, nullptr, nullptr, 4096, 3072, 1024);
  k_vt<<<dim3(32, 32), blk, 0, stream>>>(qkv + 2048, 3072, vT1, 2048);
  k_attn<<<dim3(16, 16, 2), blk, 0, stream>>>(qkv, 3072, qkv + 1024, 3072, vT1, ao, 2048);
  k_gemm_t<64, 2><<<dim3(16, 32), blk, 0, stream>>>(ao, wto1, nullptr, xres, a1bo, x, 4096, 1024, 1024);

  // ---- block 2: cross-attention ----
  k_adaln<<<4096, blk, 0, stream>>>(xres, emb2, h);
  k_gemm_t<64, 2><<<dim3(16, 32), blk, 0, stream>>>(h, wtq2, q2, nullptr, nullptr, nullptr, 4096, 1024, 1024);
  k_gemm_t<128, 1><<<dim3(16, 4), blk, 0, stream>>>(ctxb, wkv2w, kv2, nullptr, nullptr, nullptr, 512, 2048, 1024);
  k_vt<<<dim3(4, 32), blk, 0, stream>>>(kv2 + 1024, 2048, vT2, 256);
  k_attn<<<dim3(16, 16, 2), blk, 0, stream>>>(q2, 1024, kv2, 2048, vT2, ao, 256);
  k_gemm_t<64, 2><<<dim3(16, 32), blk, 0, stream>>>(ao, wto2, nullptr, xres, a2bo, xres, 4096, 1024, 1024);

  // ---- block 3: gated-GELU FFN ----
  k_adaln<<<4096, blk, 0, stream>>>(xres, emb3, h);
  k_gemm_glu<<<dim3(64, 32), blk, 0, stream>>>(h, wtf1, fb1, g, 4096, 4096, 1024);
  k_gemm_t<64, 2><<<dim3(16, 32), blk, 0, stream>>>(g, wtf2, nullptr, out, fb2, xres, 4096, 1024, 4096);
}

// Round 6
// 611.630 us; speedup vs baseline: 1.0498x; 1.0098x over previous
//
#include <hip/hip_runtime.h>
#include <hip/hip_bf16.h>
#include <math.h>
#include <stdint.h>

typedef __bf16 bf16;
typedef __attribute__((ext_vector_type(8))) __bf16 bf16x8;
typedef __attribute__((ext_vector_type(4))) __bf16 bf16x4;
typedef __attribute__((ext_vector_type(4))) float f32x4;
typedef __attribute__((ext_vector_type(16))) float f32x16;

static constexpr int cB = 2, cS = 2048, cCTX = 256, cD = 1024, cH = 16, cDH = 64, cDFF = 4096;

// async 16B global->LDS. HW semantics: dest = wave-uniform base + lane*16.
// Every call site MUST have lane i's lds ptr == base + 16*i bytes.
__device__ __forceinline__ void glds16(const bf16* g, bf16* l) {
  __builtin_amdgcn_global_load_lds(
      (const __attribute__((address_space(1))) void*)g,
      (__attribute__((address_space(3))) void*)l, 16, 0, 0);
}

// ---------------- batched transpose+convert: 8x fp32 [1024,1024] -> bf16 [1024,1024]^T ----------------
struct T8 { const float* s[8]; };
__global__ __launch_bounds__(256) void k_transpose8(T8 args, bf16* __restrict__ out) {
  __shared__ bf16 tile[64][66];
  const int n0 = blockIdx.x * 64, k0 = blockIdx.y * 64;
  const int z = blockIdx.z;
  const float* in = args.s[z];
  bf16* dst_base = out + (size_t)z * 1024 * 1024;
  const int t = threadIdx.x;
  const int r = t >> 2, cb = (t & 3) * 16;
  const float* src = in + (size_t)(k0 + r) * 1024 + n0 + cb;
#pragma unroll
  for (int q4 = 0; q4 < 4; ++q4) {
    f32x4 v = *(const f32x4*)(src + q4 * 4);
#pragma unroll
    for (int e = 0; e < 4; ++e) tile[r][cb + q4 * 4 + e] = (bf16)v[e];
  }
  __syncthreads();
  bf16* dst = dst_base + (size_t)(n0 + r) * 1024 + k0 + cb;
  bf16x8 o0, o1;
#pragma unroll
  for (int e = 0; e < 8; ++e) { o0[e] = tile[cb + e][r]; o1[e] = tile[cb + 8 + e][r]; }
  *(bf16x8*)(dst) = o0;
  *(bf16x8*)(dst + 8) = o1;
}

// ---------------- transpose+convert: fp32 [K,N] -> bf16 [N,K] (for ff weights) ----------------
__global__ __launch_bounds__(256) void k_transpose(const float* __restrict__ in,
                                                   bf16* __restrict__ out, int K, int N) {
  __shared__ bf16 tile[64][66];
  const int n0 = blockIdx.x * 64, k0 = blockIdx.y * 64;
  const int t = threadIdx.x;
  const int r = t >> 2, cb = (t & 3) * 16;
  const float* src = in + (size_t)(k0 + r) * N + n0 + cb;
#pragma unroll
  for (int q4 = 0; q4 < 4; ++q4) {
    f32x4 v = *(const f32x4*)(src + q4 * 4);
#pragma unroll
    for (int e = 0; e < 4; ++e) tile[r][cb + q4 * 4 + e] = (bf16)v[e];
  }
  __syncthreads();
  bf16* dst = out + (size_t)(n0 + r) * K + k0 + cb;
  bf16x8 o0, o1;
#pragma unroll
  for (int e = 0; e < 8; ++e) { o0[e] = tile[cb + e][r]; o1[e] = tile[cb + 8 + e][r]; }
  *(bf16x8*)(dst) = o0;
  *(bf16x8*)(dst + 8) = o1;
}

// ---------------- V transpose -> VT[(b*16+h)*64+d][kvlen] ----------------
__global__ __launch_bounds__(256) void k_vt(const bf16* __restrict__ V, int vstride,
                                            bf16* __restrict__ VT, int kvlen) {
  __shared__ bf16 tile[64][72];
  const int kt = blockIdx.x * 64, bh = blockIdx.y;
  const int b = bh >> 4, h = bh & 15;
  const int t = threadIdx.x, r = t >> 2, cb = (t & 3) * 16;
  const bf16* src = V + (size_t)(b * kvlen + kt + r) * vstride + h * 64 + cb;
  bf16x8 a0 = *(const bf16x8*)src;
  bf16x8 a1 = *(const bf16x8*)(src + 8);
#pragma unroll
  for (int e = 0; e < 8; ++e) { tile[r][cb + e] = a0[e]; tile[r][cb + 8 + e] = a1[e]; }
  __syncthreads();
  bf16* dst = VT + ((size_t)bh * 64 + r) * kvlen + kt + cb;
  bf16x8 o0, o1;
#pragma unroll
  for (int e = 0; e < 8; ++e) { o0[e] = tile[cb + e][r]; o1[e] = tile[cb + 8 + e][r]; }
  *(bf16x8*)(dst) = o0;
  *(bf16x8*)(dst + 8) = o1;
}

// ---------------- fp32 -> bf16 elementwise ----------------
__global__ __launch_bounds__(256) void k_f2b(const float* __restrict__ in, bf16* __restrict__ out) {
  const int base = (blockIdx.x * 256 + threadIdx.x) * 4;
  f32x4 v = *(const f32x4*)(in + base);
  bf16x4 o;
#pragma unroll
  for (int e = 0; e < 4; ++e) o[e] = (bf16)v[e];
  *(bf16x4*)(out + base) = o;
}

// ---------------- merged emb: emb_i = t @ W_i + b_i -> fp32 [3][2,2048] ----------------
struct EmbArgs { const float* w0; const float* w1; const float* w2;
                 const float* b0; const float* b1; const float* b2; };
__global__ __launch_bounds__(256) void k_emb3(const float* __restrict__ t, EmbArgs ea,
                                              float* __restrict__ emb) {
  const int which = blockIdx.y;
  const float* w = which == 0 ? ea.w0 : (which == 1 ? ea.w1 : ea.w2);
  const float* bias = which == 0 ? ea.b0 : (which == 1 ? ea.b1 : ea.b2);
  float* dst = emb + which * 4096;
  const int jj = threadIdx.x & 63;
  const int j = blockIdx.x * 64 + jj;
  const int kg = threadIdx.x >> 6;
  float a0 = 0.f, a1 = 0.f;
  for (int k = kg * 256; k < kg * 256 + 256; ++k) {
    float wv = w[(size_t)k * 2048 + j];
    a0 += t[k] * wv;
    a1 += t[1024 + k] * wv;
  }
  __shared__ float s0[4][64], s1[4][64];
  s0[kg][jj] = a0;
  s1[kg][jj] = a1;
  __syncthreads();
  if (threadIdx.x < 64) {
    dst[j] = s0[0][jj] + s0[1][jj] + s0[2][jj] + s0[3][jj] + bias[j];
    dst[2048 + j] = s1[0][jj] + s1[1][jj] + s1[2][jj] + s1[3][jj] + bias[j];
  }
}

// ---------------- AdaLN ----------------
__global__ __launch_bounds__(256) void k_adaln(const float* __restrict__ xres,
                                               const float* __restrict__ emb,
                                               bf16* __restrict__ h) {
  const int token = blockIdx.x;
  const int b = token >> 11;
  const float* x = xres + (size_t)token * 1024;
  const float* sc = emb + b * 2048;
  const int t = threadIdx.x;
  float v[4], s = 0.f, sq = 0.f;
#pragma unroll
  for (int i = 0; i < 4; ++i) {
    float u = x[t + 256 * i];
    v[i] = u; s += u; sq += u * u;
  }
#pragma unroll
  for (int off = 1; off < 64; off <<= 1) {
    s += __shfl_xor(s, off);
    sq += __shfl_xor(sq, off);
  }
  __shared__ float ss[4], ssq[4];
  const int wave = t >> 6;
  if ((t & 63) == 0) { ss[wave] = s; ssq[wave] = sq; }
  __syncthreads();
  const float S_ = ss[0] + ss[1] + ss[2] + ss[3];
  const float SQ = ssq[0] + ssq[1] + ssq[2] + ssq[3];
  const float mean = S_ * (1.f / 1024.f);
  const float var = SQ * (1.f / 1024.f) - mean * mean;
  const float rstd = rsqrtf(var + 1e-5f);
#pragma unroll
  for (int i = 0; i < 4; ++i) {
    const int c = t + 256 * i;
    float val = (v[i] - mean) * rstd * (1.f + sc[c]) + sc[1024 + c];
    h[(size_t)token * 1024 + c] = (bf16)val;
  }
}

// ---------------- GEMM (32x32x16 MFMA): C[M,N] = A[M,K] @ Bt[N,K]^T (+bias)(+res) ----------------
// DB=1: original 2-barrier structure (for TN=128 sites at 3+ blocks/CU).
// DB=2: minimum-2-phase (T3 minimum): stage(buf^1) issued BEFORE compute(buf),
//       one vmcnt(0)+barrier per K-step -> staged loads fly under the MFMA.
template <int TN, int DB>
__global__ __launch_bounds__(256) void k_gemm_t(const bf16* __restrict__ A,
                                                const bf16* __restrict__ Bt,
                                                bf16* Cb, float* Cf,
                                                const float* __restrict__ bias,
                                                const float* res,
                                                int M, int N, int K) {
  constexpr int CJ = TN / 64;  // 32-col MFMA tiles per wave (1 or 2)
  __shared__ bf16 As[DB][2 * 128 * 32];
  __shared__ bf16 Bs[DB][2 * TN * 32];
  const int m0 = blockIdx.y * 128, n0 = blockIdx.x * TN;
  const int tid = threadIdx.x;
  const int wave = tid >> 6, lane = tid & 63;
  const int l31 = lane & 31, hi8 = (lane >> 5) * 8;
  const int mw = (wave >> 1) * 64, nw = (wave & 1) * (TN / 2);
  f32x16 acc[2][CJ];
#pragma unroll
  for (int i = 0; i < 2; ++i)
#pragma unroll
    for (int j = 0; j < CJ; ++j) acc[i][j] = (f32x16)(0.f);

  const int r0 = tid >> 2, c0 = (tid & 3) << 3;
  const bf16* Ap = A + (size_t)(m0 + r0) * K + c0;
  const bf16* Bp = Bt + (size_t)(n0 + r0) * K + c0;
  bf16* lA0 = &As[0][0] + r0 * 32 + c0;
  bf16* lB0 = &Bs[0][0] + r0 * 32 + c0;

#define STAGE_GT(buf, k0)                                                       \
  do {                                                                          \
    bf16* lA = lA0 + (buf) * (2 * 128 * 32);                                    \
    bf16* lB = lB0 + (buf) * (2 * TN * 32);                                     \
    glds16(Ap + (k0), lA);                                                      \
    glds16(Ap + (k0) + (size_t)64 * K, lA + 64 * 32);                           \
    glds16(Ap + (k0) + 32, lA + 128 * 32);                                      \
    glds16(Ap + (k0) + 32 + (size_t)64 * K, lA + 192 * 32);                     \
    glds16(Bp + (k0), lB);                                                      \
    if (TN == 128) glds16(Bp + (k0) + (size_t)64 * K, lB + 64 * 32);            \
    glds16(Bp + (k0) + 32, lB + TN * 32);                                       \
    if (TN == 128) glds16(Bp + (k0) + 32 + (size_t)64 * K, lB + TN * 32 + 64 * 32); \
  } while (0)

#define COMPUTE_GT(buf)                                                          \
  do {                                                                           \
    _Pragma("unroll")                                                            \
    for (int kp = 0; kp < 2; ++kp) {                                             \
      const bf16* Asp = &As[buf][0] + kp * 128 * 32;                             \
      const bf16* Bsp = &Bs[buf][0] + kp * TN * 32;                              \
      _Pragma("unroll")                                                          \
      for (int kh = 0; kh < 2; ++kh) {                                           \
        bf16x8 af[2], bfr[CJ];                                                   \
        _Pragma("unroll")                                                        \
        for (int i = 0; i < 2; ++i)                                              \
          af[i] = *(const bf16x8*)(Asp + (mw + i * 32 + l31) * 32 + kh * 16 + hi8); \
        _Pragma("unroll")                                                        \
        for (int j = 0; j < CJ; ++j)                                             \
          bfr[j] = *(const bf16x8*)(Bsp + (nw + j * 32 + l31) * 32 + kh * 16 + hi8); \
        _Pragma("unroll")                                                        \
        for (int i = 0; i < 2; ++i)                                              \
          _Pragma("unroll")                                                      \
          for (int j = 0; j < CJ; ++j)                                           \
            acc[i][j] = __builtin_amdgcn_mfma_f32_32x32x16_bf16(af[i], bfr[j], acc[i][j], 0, 0, 0); \
      }                                                                          \
    }                                                                            \
  } while (0)

  if (DB == 2) {
    STAGE_GT(0, 0);
    __syncthreads();
    for (int k0 = 0; k0 < K; k0 += 64) {
      const int cur = (k0 >> 6) & 1;
      if (k0 + 64 < K) STAGE_GT(cur ^ 1, k0 + 64);
      COMPUTE_GT(cur);
      __syncthreads();
    }
  } else {
    for (int k0 = 0; k0 < K; k0 += 64) {
      __syncthreads();
      STAGE_GT(0, k0);
      __syncthreads();
      COMPUTE_GT(0);
    }
  }
#undef STAGE_GT
#undef COMPUTE_GT

#pragma unroll
  for (int i = 0; i < 2; ++i) {
    const int rb = m0 + mw + i * 32 + 4 * (lane >> 5);
#pragma unroll
    for (int j = 0; j < CJ; ++j) {
      const int col = n0 + nw + j * 32 + l31;
      const float bv = bias ? bias[col] : 0.f;
#pragma unroll
      for (int reg = 0; reg < 16; ++reg) {
        const int row = rb + (reg & 3) + 8 * (reg >> 2);
        const size_t off = (size_t)row * N + col;
        float v2 = acc[i][j][reg] + bv;
        if (res) v2 += res[off];
        if (Cf) Cf[off] = v2;
        if (Cb) Cb[off] = (bf16)v2;
      }
    }
  }
}

// ---------------- FF1: 8-phase 256-row x (128a+128g col) GLU GEMM, v2 with T2 swizzle ----------------
// Schedule identical to the R1-refcheck-passed version (T3+T4 counted vmcnt(6)
// at phases 4/8, T5 setprio, T1 XCD map). v2 fixes the R1 perf bug: the
// [256][32el] half-panels had bank-start (row*16+hi*4)%32 = only 2 values
// across 16 fragment rows -> 8-way conflict on EVERY A/B ds_read_b128.
// T2 fix (rule #21): linear glds16 dest; global SOURCE chunk ^= ((lane>>3)&3)
// (constant: staging rows = wid*32+(lane>>2), row>>1 & 3 = (lane>>3)&3 since
// wid*16 === 0 mod 4); fragment read physical chunk = hi ^ ((l15>>1)&3)
// (constant: fragment rows = base + l15 with base === 0 mod 8). Post-swizzle
// bank-start = (l15&1)*16 + (hi^((l15>>1)&3))*4 -> 8 slots x 2 lanes = free.
__global__ __launch_bounds__(512, 2) void k_glu8(const bf16* __restrict__ A,
                                                 const bf16* __restrict__ Bt,
                                                 const float* __restrict__ bias,
                                                 bf16* __restrict__ C) {
  constexpr int K = 1024, NOUT = 4096, NT = K / 64, NIT = NT / 2;
  __shared__ __align__(16) bf16 sA[2 * 2 * 8192];   // [buf][khalf][256][32]
  __shared__ __align__(16) bf16 sB[2 * 2 * 8192];

  // 512 blocks -> 8 XCDs x 64; within an XCD: 4 n-strips x 16 m (m-fast so the
  // XCD's L2 holds its 4 B-panels, A panels stream).
  const int bid = blockIdx.x;
  const int xcd = bid & 7, bj = bid >> 3;
  const int n_idx = xcd * 4 + (bj >> 4);
  const int m_idx = bj & 15;
  const int m0 = m_idx * 256, n0 = n_idx * 128;

  const int tid = threadIdx.x;
  const int wid = tid >> 6, lane = tid & 63;
  const int l15 = lane & 15, hi = lane >> 4;
  const int wm = wid >> 2, wn = wid & 3;     // 2 x 4 wave grid

  // staging: each wave covers 32 rows of a [256][32] half-panel; 2 glds16 of
  // 1024B each (16 rows). lane covers row (lane>>2), 16B chunk (lane&3),
  // source chunk pre-swizzled by ((lane>>3)&3).
  const int srA = wid * 32 + (lane >> 2);
  const int scol = ((lane & 3) ^ ((lane >> 3) & 3)) * 8;
  const bf16* aS0 = A + (size_t)(m0 + srA) * K + scol;
  const bf16* aS1 = aS0 + (size_t)16 * K;
  auto grow = [&](int r) {   // B LDS row -> global Bt row (a/gate interleave)
    return n0 + (r >> 6) * 32 + (r & 31) + ((r & 32) ? NOUT : 0);
  };
  const bf16* bS0 = Bt + (size_t)grow(srA) * K + scol;
  const bf16* bS1 = Bt + (size_t)grow(srA + 16) * K + scol;
  bf16* aD = sA + wid * 1024 + lane * 8;
  bf16* bD = sB + wid * 1024 + lane * 8;
  const int rxor = (hi ^ ((l15 >> 1) & 3)) * 8;   // read-side physical chunk
  const bf16* aF = sA + (wm * 128 + l15) * 32 + rxor;
  const bf16* bF = sB + (wn * 64 + l15) * 32 + rxor;

  f32x4 acc[8][4];
#pragma unroll
  for (int i = 0; i < 8; ++i)
#pragma unroll
    for (int n = 0; n < 4; ++n) acc[i][n] = (f32x4){0.f, 0.f, 0.f, 0.f};
  bf16x8 aq[4], bq[4];

#define STG_A(bb, kh, kt) do { \
    glds16(aS0 + (kt) * 64 + (kh) * 32, aD + ((bb) * 2 + (kh)) * 8192); \
    glds16(aS1 + (kt) * 64 + (kh) * 32, aD + ((bb) * 2 + (kh)) * 8192 + 512); } while (0)
#define STG_B(bb, kh, kt) do { \
    glds16(bS0 + (kt) * 64 + (kh) * 32, bD + ((bb) * 2 + (kh)) * 8192); \
    glds16(bS1 + (kt) * 64 + (kh) * 32, bD + ((bb) * 2 + (kh)) * 8192 + 512); } while (0)

#define PH(bb, kh, mh, STAGES, VMC) do { \
    if ((mh) == 0) { \
      _Pragma("unroll") \
      for (int nf = 0; nf < 4; ++nf) \
        bq[nf] = *(const bf16x8*)(bF + ((bb) * 2 + (kh)) * 8192 + nf * 512); \
    } \
    _Pragma("unroll") \
    for (int mi = 0; mi < 4; ++mi) \
      aq[mi] = *(const bf16x8*)(aF + ((bb) * 2 + (kh)) * 8192 + ((mh) * 4 + mi) * 512); \
    STAGES; \
    __builtin_amdgcn_s_barrier(); \
    asm volatile("s_waitcnt lgkmcnt(0)" ::: "memory"); \
    __builtin_amdgcn_sched_barrier(0); \
    __builtin_amdgcn_s_setprio(1); \
    _Pragma("unroll") \
    for (int mi = 0; mi < 4; ++mi) \
      _Pragma("unroll") \
      for (int nf = 0; nf < 4; ++nf) \
        acc[(mh) * 4 + mi][nf] = __builtin_amdgcn_mfma_f32_16x16x32_bf16( \
            aq[mi], bq[nf], acc[(mh) * 4 + mi][nf], 0, 0, 0); \
    __builtin_amdgcn_s_setprio(0); \
    VMC; \
    __builtin_amdgcn_s_barrier(); \
    __builtin_amdgcn_sched_barrier(0); \
  } while (0)

  // prologue: tile0 fully + tile1 {B-K0, A-K0, B-K1}; vmcnt(6) -> tile0 landed.
  STG_B(0, 0, 0); STG_A(0, 0, 0); STG_B(0, 1, 0); STG_A(0, 1, 0);
  STG_B(1, 0, 1); STG_A(1, 0, 1); STG_B(1, 1, 1);
  asm volatile("s_waitcnt vmcnt(6)" ::: "memory");
  __builtin_amdgcn_s_barrier();
  __builtin_amdgcn_sched_barrier(0);

  for (int it = 0; it < NIT; ++it) {
    const int T = 2 * it;
    const int t2 = (T + 2 < NT) ? (T + 2) : 0;   // clamped dead prefetch on tail
    const int t3 = (T + 3 < NT) ? (T + 3) : 0;
    PH(0, 0, 0, STG_A(1, 1, T + 1), );
    PH(0, 0, 1, STG_B(0, 0, t2), );
    PH(0, 1, 0, STG_A(0, 0, t2), );
    PH(0, 1, 1, STG_B(0, 1, t2), asm volatile("s_waitcnt vmcnt(6)" ::: "memory"));
    PH(1, 0, 0, STG_A(0, 1, t2), );
    PH(1, 0, 1, STG_B(1, 0, t3), );
    PH(1, 1, 0, STG_A(1, 0, t3), );
    PH(1, 1, 1, STG_B(1, 1, t3), asm volatile("s_waitcnt vmcnt(6)" ::: "memory"));
  }
#undef PH
#undef STG_A
#undef STG_B

  // GLU epilogue: acc[.][0..1] = a, acc[.][2..3] = gate for the same columns.
#pragma unroll
  for (int mi = 0; mi < 8; ++mi) {
    const int row = m0 + wm * 128 + mi * 16 + hi * 4;
#pragma unroll
    for (int nf = 0; nf < 2; ++nf) {
      const int col = n0 + wn * 32 + nf * 16 + l15;
      const float bav = bias[col], bgv = bias[NOUT + col];
#pragma unroll
      for (int r = 0; r < 4; ++r) {
        float a = acc[mi][nf][r] + bav;
        float g = acc[mi][nf + 2][r] + bgv;
        float ge = 0.5f * g * (1.0f + erff(g * 0.70710678118654752f));
        C[(size_t)(row + r) * NOUT + col] = (bf16)(a * ge);
      }
    }
  }
}

// ---------------- flash attention, fixed-max softmax, 128 Q-rows/block ----------------
// min-2-phase K/V pipeline + XOR-swizzled K/V tiles.
// Swizzle (rule #21): linear LDS dest; global SOURCE chunk = c ^ (row&7);
// read physical chunk = logical ^ (row&7). [64][64el] rows are 128B, so the
// unswizzled ds_read_b128 was a 16-way bank conflict (each 16-lane group hits
// the same 4 banks); post-swizzle 2 lanes/chunk across all 32 banks = free.
__global__ __launch_bounds__(256) void k_attn(const bf16* __restrict__ Qp, int qstride,
                                              const bf16* __restrict__ Kp, int kstride,
                                              const bf16* __restrict__ VTp,
                                              bf16* __restrict__ Op, int kvlen) {
  const int qt = blockIdx.x * 128;
  const int hd = blockIdx.y;
  const int b = blockIdx.z;
  const int tid = threadIdx.x;
  const int wave = tid >> 6, lane = tid & 63;
  const int quad = lane >> 4, l16 = lane & 15;
  const int rswq = l16 & 7;                  // read-side chunk XOR (row&7 of read row)

  __shared__ __align__(16) bf16 Ks[2][64 * 64];
  __shared__ __align__(16) bf16 Vs[2][64 * 64];
  __shared__ __align__(16) bf16 Ps[4][32 * 72];

  bf16x8 qf[2][2];
#pragma unroll
  for (int g = 0; g < 2; ++g) {
    const bf16* qrow = Qp + (size_t)(b * cS + qt + wave * 32 + g * 16 + l16) * qstride + hd * 64;
#pragma unroll
    for (int c = 0; c < 2; ++c) {
      bf16x8 raw = *(const bf16x8*)(qrow + c * 32 + quad * 8);
#pragma unroll
      for (int e = 0; e < 8; ++e) qf[g][c][e] = (bf16)((float)raw[e] * 0.125f);
    }
  }

  float l_part[2][4] = {{0.f, 0.f, 0.f, 0.f}, {0.f, 0.f, 0.f, 0.f}};
  f32x4 o_acc[2][4];
#pragma unroll
  for (int g = 0; g < 2; ++g)
#pragma unroll
    for (int n = 0; n < 4; ++n) o_acc[g][n] = (f32x4){0.f, 0.f, 0.f, 0.f};

  const int lrow = wave * 16 + (lane >> 3);                // staged row (row&7 = (lane>>3)&7)
  const int lcol = (lane & 7) * 8;                         // linear LDS dest chunk
  const int scol = (((lane & 7) ^ ((lane >> 3) & 7)) * 8); // inverse-swizzled global src
  const bf16* kbase = Kp + (size_t)(b * kvlen + lrow) * kstride + hd * 64 + scol;
  const bf16* vbase = VTp + ((size_t)((b * 16 + hd) * 64 + lrow)) * kvlen + scol;
  bf16* lk0 = &Ks[0][0] + lrow * 64 + lcol;
  bf16* lv0 = &Vs[0][0] + lrow * 64 + lcol;

#define STAGE_AT(buf, kt)                                              \
  do {                                                                 \
    const bf16* kg = kbase + (size_t)(kt) * kstride;                   \
    bf16* lk = lk0 + (buf) * (64 * 64);                                \
    bf16* lv = lv0 + (buf) * (64 * 64);                                \
    glds16(kg, lk);                                                    \
    glds16(kg + (size_t)8 * kstride, lk + 8 * 64);                     \
    glds16(vbase + (kt), lv);                                          \
    glds16(vbase + (kt) + (size_t)8 * kvlen, lv + 8 * 64);             \
  } while (0)

  STAGE_AT(0, 0);
  __syncthreads();

  for (int kt = 0; kt < kvlen; kt += 64) {
    const int cur = (kt >> 6) & 1;
    if (kt + 64 < kvlen) STAGE_AT(cur ^ 1, kt + 64);

    f32x4 s[2][4];
#pragma unroll
    for (int g = 0; g < 2; ++g)
#pragma unroll
      for (int t = 0; t < 4; ++t) s[g][t] = (f32x4){0.f, 0.f, 0.f, 0.f};
#pragma unroll
    for (int t = 0; t < 4; ++t)
#pragma unroll
      for (int c = 0; c < 2; ++c) {
        bf16x8 kf = *(const bf16x8*)(&Ks[cur][0] + (t * 16 + l16) * 64 + (((c * 4 + quad) ^ rswq) << 3));
#pragma unroll
        for (int g = 0; g < 2; ++g)
          s[g][t] = __builtin_amdgcn_mfma_f32_16x16x32_bf16(qf[g][c], kf, s[g][t], 0, 0, 0);
      }

#pragma unroll
    for (int g = 0; g < 2; ++g)
#pragma unroll
      for (int t = 0; t < 4; ++t)
#pragma unroll
        for (int r = 0; r < 4; ++r) {
          float p = __expf(s[g][t][r]);
          Ps[wave][(g * 16 + quad * 4 + r) * 72 + t * 16 + l16] = (bf16)p;
          l_part[g][r] += p;
        }

    bf16x8 pf[2][2];
#pragma unroll
    for (int g = 0; g < 2; ++g)
#pragma unroll
      for (int c = 0; c < 2; ++c)
        pf[g][c] = *(const bf16x8*)(&Ps[wave][(g * 16 + l16) * 72 + c * 32 + quad * 8]);
#pragma unroll
    for (int n = 0; n < 4; ++n)
#pragma unroll
      for (int c = 0; c < 2; ++c) {
        bf16x8 vf = *(const bf16x8*)(&Vs[cur][0] + (n * 16 + l16) * 64 + (((c * 4 + quad) ^ rswq) << 3));
#pragma unroll
        for (int g = 0; g < 2; ++g)
          o_acc[g][n] = __builtin_amdgcn_mfma_f32_16x16x32_bf16(pf[g][c], vf, o_acc[g][n], 0, 0, 0);
      }
    __syncthreads();
  }
#undef STAGE_AT

#pragma unroll
  for (int g = 0; g < 2; ++g) {
    float rl[4];
#pragma unroll
    for (int r = 0; r < 4; ++r) {
      float v = l_part[g][r];
      v += __shfl_xor(v, 1);
      v += __shfl_xor(v, 2);
      v += __shfl_xor(v, 4);
      v += __shfl_xor(v, 8);
      rl[r] = 1.f / v;
    }
#pragma unroll
    for (int n = 0; n < 4; ++n)
#pragma unroll
      for (int r = 0; r < 4; ++r) {
        const int srow = qt + wave * 32 + g * 16 + quad * 4 + r;
        const int d = n * 16 + l16;
        Op[(size_t)(b * cS + srow) * 1024 + hd * 64 + d] = (bf16)(o_acc[g][n][r] * rl[r]);
      }
  }
}

// ---------------- launch ----------------
extern "C" void kernel_launch(void* const* d_in, const int* in_sizes, int n_in,
                              void* d_out, int out_size, void* d_ws, size_t ws_size,
                              hipStream_t stream) {
  const float* x    = (const float*)d_in[0];
  const float* tt   = (const float*)d_in[1];
  const float* ctx  = (const float*)d_in[2];
  const float* fw1  = (const float*)d_in[13];
  const float* fb1  = (const float*)d_in[14];
  const float* fw2  = (const float*)d_in[15];
  const float* fb2  = (const float*)d_in[16];
  const float* a1bo = (const float*)d_in[7];
  const float* a2bo = (const float*)d_in[12];

  char* ws = (char*)d_ws;
  const size_t MB = 1ull << 20;
  // 8 square transposed weights packed: [q1,k1,v1,o1,q2,k2,v2,o2] x 2 MB
  bf16* wsq   = (bf16*)(ws + 0 * MB);
  bf16* wqkv1 = wsq;                               // mats 0-2
  bf16* wto1  = (bf16*)(ws + 6 * MB);              // mat 3
  bf16* wtq2  = (bf16*)(ws + 8 * MB);              // mat 4
  bf16* wkv2w = (bf16*)(ws + 10 * MB);             // mats 5-6
  bf16* wto2  = (bf16*)(ws + 14 * MB);             // mat 7
  bf16* wtf1  = (bf16*)(ws + 16 * MB);             // [8192,1024], 16 MB
  bf16* wtf2  = (bf16*)(ws + 32 * MB);             // [1024,4096], 8 MB
  float* emb  = (float*)(ws + 40 * MB);            // 3 x [2,2048]
  float* emb1 = emb, *emb2 = emb + 4096, *emb3 = emb + 8192;
  bf16* ctxb  = (bf16*)(ws + 40 * MB + 262144);    // [512,1024], 1 MB
  float* xres = (float*)(ws + 42 * MB);            // fp32 residual, 16 MB
  bf16* h     = (bf16*)(ws + 58 * MB);             // 8 MB
  bf16* ao    = h;
  bf16* qkv   = (bf16*)(ws + 66 * MB);             // [4096,3072], 24 MB
  bf16* q2    = qkv;
  bf16* vT1   = (bf16*)(ws + 90 * MB);             // [32*64,2048], 8 MB
  bf16* kv2   = (bf16*)(ws + 0 * MB);              // [512,2048], 2 MB (aliases dead mats 0-1)
  bf16* vT2   = (bf16*)(ws + 2 * MB);              // [32*64,256], 1 MB (aliases dead mat 1)
  bf16* g     = (bf16*)(ws + 66 * MB);             // [4096,4096], 32 MB
  float* out  = (float*)d_out;

  const dim3 blk(256);

  T8 t8;
  t8.s[0] = (const float*)d_in[3];   // a1wq
  t8.s[1] = (const float*)d_in[4];   // a1wk
  t8.s[2] = (const float*)d_in[5];   // a1wv
  t8.s[3] = (const float*)d_in[6];   // a1wo
  t8.s[4] = (const float*)d_in[8];   // a2wq
  t8.s[5] = (const float*)d_in[9];   // a2wk
  t8.s[6] = (const float*)d_in[10];  // a2wv
  t8.s[7] = (const float*)d_in[11];  // a2wo
  k_transpose8<<<dim3(16, 16, 8), blk, 0, stream>>>(t8, wsq);
  k_transpose<<<dim3(128, 16), blk, 0, stream>>>(fw1, wtf1, 1024, 8192);
  k_transpose<<<dim3(16, 64), blk, 0, stream>>>(fw2, wtf2, 4096, 1024);

  EmbArgs ea;
  ea.w0 = (const float*)d_in[17]; ea.b0 = (const float*)d_in[18];
  ea.w1 = (const float*)d_in[19]; ea.b1 = (const float*)d_in[20];
  ea.w2 = (const float*)d_in[21]; ea.b2 = (const float*)d_in[22];
  k_emb3<<<dim3(32, 3), blk, 0, stream>>>(tt, ea, emb);
  k_f2b<<<512, blk, 0, stream>>>(ctx, ctxb);

  // ---- block 1: self-attention ----
  k_adaln<<<4096, blk, 0, stream>>>(x, emb1, h);
  k_gemm_t<128, 1><<<dim3(24, 32), blk, 0, stream>>>(h, wqkv1, qkv, nullptr, nullptr, nullptr, 4096, 3072, 1024);
  k_vt<<<dim3(32, 32), blk, 0, stream>>>(qkv + 2048, 3072, vT1, 2048);
  k_attn<<<dim3(16, 16, 2), blk, 0, stream>>>(qkv, 3072, qkv + 1024, 3072, vT1, ao, 2048);
  k_gemm_t<64, 2><<<dim3(16, 32), blk, 0, stream>>>(ao, wto1, nullptr, xres, a1bo, x, 4096, 1024, 1024);

  // ---- block 2: cross-attention ----
  k_adaln<<<4096, blk, 0, stream>>>(xres, emb2, h);
  k_gemm_t<64, 2><<<dim3(16, 32), blk, 0, stream>>>(h, wtq2, q2, nullptr, nullptr, nullptr, 4096, 1024, 1024);
  k_gemm_t<128, 1><<<dim3(16, 4), blk, 0, stream>>>(ctxb, wkv2w, kv2, nullptr, nullptr, nullptr, 512, 2048, 1024);
  k_vt<<<dim3(4, 32), blk, 0, stream>>>(kv2 + 1024, 2048, vT2, 256);
  k_attn<<<dim3(16, 16, 2), blk, 0, stream>>>(q2, 1024, kv2, 2048, vT2, ao, 256);
  k_gemm_t<64, 2><<<dim3(16, 32), blk, 0, stream>>>(ao, wto2, nullptr, xres, a2bo, xres, 4096, 1024, 1024);

  // ---- block 3: gated-GELU FFN ----
  k_adaln<<<4096, blk, 0, stream>>>(xres, emb3, h);
  k_glu8<<<dim3(512), dim3(512), 0, stream>>>(h, wtf1, fb1, g);
  k_gemm_t<64, 2><<<dim3(16, 32), blk, 0, stream>>>(g, wtf2, nullptr, out, fb2, xres, 4096, 1024, 4096);
}

// Round 7
// 594.189 us; speedup vs baseline: 1.0806x; 1.0294x over previous
//
#include <hip/hip_runtime.h>
#include <hip/hip_bf16.h>
#include <math.h>
#include <stdint.h>

typedef __bf16 bf16;
typedef __attribute__((ext_vector_type(8))) __bf16 bf16x8;
typedef __attribute__((ext_vector_type(4))) __bf16 bf16x4;
typedef __attribute__((ext_vector_type(4))) float f32x4;
typedef __attribute__((ext_vector_type(16))) float f32x16;

static constexpr int cB = 2, cS = 2048, cCTX = 256, cD = 1024, cH = 16, cDH = 64, cDFF = 4096;

// async 16B global->LDS. HW semantics: dest = wave-uniform base + lane*16.
// Every call site MUST have lane i's lds ptr == base + 16*i bytes.
__device__ __forceinline__ void glds16(const bf16* g, bf16* l) {
  __builtin_amdgcn_global_load_lds(
      (const __attribute__((address_space(1))) void*)g,
      (__attribute__((address_space(3))) void*)l, 16, 0, 0);
}

// ---------------- batched transpose+convert: 8x fp32 [1024,1024] -> bf16 [1024,1024]^T ----------------
struct T8 { const float* s[8]; };
__global__ __launch_bounds__(256) void k_transpose8(T8 args, bf16* __restrict__ out) {
  __shared__ bf16 tile[64][66];
  const int n0 = blockIdx.x * 64, k0 = blockIdx.y * 64;
  const int z = blockIdx.z;
  const float* in = args.s[z];
  bf16* dst_base = out + (size_t)z * 1024 * 1024;
  const int t = threadIdx.x;
  const int r = t >> 2, cb = (t & 3) * 16;
  const float* src = in + (size_t)(k0 + r) * 1024 + n0 + cb;
#pragma unroll
  for (int q4 = 0; q4 < 4; ++q4) {
    f32x4 v = *(const f32x4*)(src + q4 * 4);
#pragma unroll
    for (int e = 0; e < 4; ++e) tile[r][cb + q4 * 4 + e] = (bf16)v[e];
  }
  __syncthreads();
  bf16* dst = dst_base + (size_t)(n0 + r) * 1024 + k0 + cb;
  bf16x8 o0, o1;
#pragma unroll
  for (int e = 0; e < 8; ++e) { o0[e] = tile[cb + e][r]; o1[e] = tile[cb + 8 + e][r]; }
  *(bf16x8*)(dst) = o0;
  *(bf16x8*)(dst + 8) = o1;
}

// ---------------- transpose+convert: fp32 [K,N] -> bf16 [N,K] (for ff weights) ----------------
__global__ __launch_bounds__(256) void k_transpose(const float* __restrict__ in,
                                                   bf16* __restrict__ out, int K, int N) {
  __shared__ bf16 tile[64][66];
  const int n0 = blockIdx.x * 64, k0 = blockIdx.y * 64;
  const int t = threadIdx.x;
  const int r = t >> 2, cb = (t & 3) * 16;
  const float* src = in + (size_t)(k0 + r) * N + n0 + cb;
#pragma unroll
  for (int q4 = 0; q4 < 4; ++q4) {
    f32x4 v = *(const f32x4*)(src + q4 * 4);
#pragma unroll
    for (int e = 0; e < 4; ++e) tile[r][cb + q4 * 4 + e] = (bf16)v[e];
  }
  __syncthreads();
  bf16* dst = out + (size_t)(n0 + r) * K + k0 + cb;
  bf16x8 o0, o1;
#pragma unroll
  for (int e = 0; e < 8; ++e) { o0[e] = tile[cb + e][r]; o1[e] = tile[cb + 8 + e][r]; }
  *(bf16x8*)(dst) = o0;
  *(bf16x8*)(dst + 8) = o1;
}

// ---------------- V transpose -> VT[(b*16+h)*64+d][kvlen] ----------------
__global__ __launch_bounds__(256) void k_vt(const bf16* __restrict__ V, int vstride,
                                            bf16* __restrict__ VT, int kvlen) {
  __shared__ bf16 tile[64][72];
  const int kt = blockIdx.x * 64, bh = blockIdx.y;
  const int b = bh >> 4, h = bh & 15;
  const int t = threadIdx.x, r = t >> 2, cb = (t & 3) * 16;
  const bf16* src = V + (size_t)(b * kvlen + kt + r) * vstride + h * 64 + cb;
  bf16x8 a0 = *(const bf16x8*)src;
  bf16x8 a1 = *(const bf16x8*)(src + 8);
#pragma unroll
  for (int e = 0; e < 8; ++e) { tile[r][cb + e] = a0[e]; tile[r][cb + 8 + e] = a1[e]; }
  __syncthreads();
  bf16* dst = VT + ((size_t)bh * 64 + r) * kvlen + kt + cb;
  bf16x8 o0, o1;
#pragma unroll
  for (int e = 0; e < 8; ++e) { o0[e] = tile[cb + e][r]; o1[e] = tile[cb + 8 + e][r]; }
  *(bf16x8*)(dst) = o0;
  *(bf16x8*)(dst + 8) = o1;
}

// ---------------- fp32 -> bf16 elementwise ----------------
__global__ __launch_bounds__(256) void k_f2b(const float* __restrict__ in, bf16* __restrict__ out) {
  const int base = (blockIdx.x * 256 + threadIdx.x) * 4;
  f32x4 v = *(const f32x4*)(in + base);
  bf16x4 o;
#pragma unroll
  for (int e = 0; e < 4; ++e) o[e] = (bf16)v[e];
  *(bf16x4*)(out + base) = o;
}

// ---------------- merged emb: emb_i = t @ W_i + b_i -> fp32 [3][2,2048] ----------------
struct EmbArgs { const float* w0; const float* w1; const float* w2;
                 const float* b0; const float* b1; const float* b2; };
__global__ __launch_bounds__(256) void k_emb3(const float* __restrict__ t, EmbArgs ea,
                                              float* __restrict__ emb) {
  const int which = blockIdx.y;
  const float* w = which == 0 ? ea.w0 : (which == 1 ? ea.w1 : ea.w2);
  const float* bias = which == 0 ? ea.b0 : (which == 1 ? ea.b1 : ea.b2);
  float* dst = emb + which * 4096;
  const int jj = threadIdx.x & 63;
  const int j = blockIdx.x * 64 + jj;
  const int kg = threadIdx.x >> 6;
  float a0 = 0.f, a1 = 0.f;
  for (int k = kg * 256; k < kg * 256 + 256; ++k) {
    float wv = w[(size_t)k * 2048 + j];
    a0 += t[k] * wv;
    a1 += t[1024 + k] * wv;
  }
  __shared__ float s0[4][64], s1[4][64];
  s0[kg][jj] = a0;
  s1[kg][jj] = a1;
  __syncthreads();
  if (threadIdx.x < 64) {
    dst[j] = s0[0][jj] + s0[1][jj] + s0[2][jj] + s0[3][jj] + bias[j];
    dst[2048 + j] = s1[0][jj] + s1[1][jj] + s1[2][jj] + s1[3][jj] + bias[j];
  }
}

// ---------------- AdaLN ----------------
__global__ __launch_bounds__(256) void k_adaln(const float* __restrict__ xres,
                                               const float* __restrict__ emb,
                                               bf16* __restrict__ h) {
  const int token = blockIdx.x;
  const int b = token >> 11;
  const float* x = xres + (size_t)token * 1024;
  const float* sc = emb + b * 2048;
  const int t = threadIdx.x;
  float v[4], s = 0.f, sq = 0.f;
#pragma unroll
  for (int i = 0; i < 4; ++i) {
    float u = x[t + 256 * i];
    v[i] = u; s += u; sq += u * u;
  }
#pragma unroll
  for (int off = 1; off < 64; off <<= 1) {
    s += __shfl_xor(s, off);
    sq += __shfl_xor(sq, off);
  }
  __shared__ float ss[4], ssq[4];
  const int wave = t >> 6;
  if ((t & 63) == 0) { ss[wave] = s; ssq[wave] = sq; }
  __syncthreads();
  const float S_ = ss[0] + ss[1] + ss[2] + ss[3];
  const float SQ = ssq[0] + ssq[1] + ssq[2] + ssq[3];
  const float mean = S_ * (1.f / 1024.f);
  const float var = SQ * (1.f / 1024.f) - mean * mean;
  const float rstd = rsqrtf(var + 1e-5f);
#pragma unroll
  for (int i = 0; i < 4; ++i) {
    const int c = t + 256 * i;
    float val = (v[i] - mean) * rstd * (1.f + sc[c]) + sc[1024 + c];
    h[(size_t)token * 1024 + c] = (bf16)val;
  }
}

// ---------------- GEMM (32x32x16 MFMA): C[M,N] = A[M,K] @ Bt[N,K]^T (+bias)(+res) ----------------
// DB=1: original 2-barrier structure (for TN=128 sites at 3+ blocks/CU).
// DB=2: minimum-2-phase (T3 minimum): stage(buf^1) issued BEFORE compute(buf),
//       one vmcnt(0)+barrier per K-step -> staged loads fly under the MFMA.
// T2 swizzle (rule #21): 64B-row panels gave bank-start 16*(l31&1)+4*(kh*2+hi)
// -> 8 lanes aliasing per chunk on every ds_read_b128 (~12 extra cy, measured
// 2.5e7 on old glu). Fix: global SOURCE chunk = c0 ^ ((r0>>1)&3) (valid for all
// staged row-groups, bases === 0 mod 64), linear LDS dest, read physical chunk
// (kh*2+hi) ^ ((l31>>1)&3) (fragment-row bases === 0 mod 32) -> 8 lanes per
// slot = 4/cycle over its 4 banks = conflict-free.
template <int TN, int DB>
__global__ __launch_bounds__(256) void k_gemm_t(const bf16* __restrict__ A,
                                                const bf16* __restrict__ Bt,
                                                bf16* Cb, float* Cf,
                                                const float* __restrict__ bias,
                                                const float* res,
                                                int M, int N, int K) {
  constexpr int CJ = TN / 64;  // 32-col MFMA tiles per wave (1 or 2)
  __shared__ bf16 As[DB][2 * 128 * 32];
  __shared__ bf16 Bs[DB][2 * TN * 32];
  const int m0 = blockIdx.y * 128, n0 = blockIdx.x * TN;
  const int tid = threadIdx.x;
  const int wave = tid >> 6, lane = tid & 63;
  const int l31 = lane & 31, hi = lane >> 5;
  const int rsw = (l31 >> 1) & 3;            // read-side chunk XOR (per-lane const)
  const int mw = (wave >> 1) * 64, nw = (wave & 1) * (TN / 2);
  f32x16 acc[2][CJ];
#pragma unroll
  for (int i = 0; i < 2; ++i)
#pragma unroll
    for (int j = 0; j < CJ; ++j) acc[i][j] = (f32x16)(0.f);

  const int r0 = tid >> 2, c0 = tid & 3;
  const int swzS = (c0 ^ ((r0 >> 1) & 3)) << 3;     // inverse-swizzled global source chunk
  const bf16* Ap = A + (size_t)(m0 + r0) * K + swzS;
  const bf16* Bp = Bt + (size_t)(n0 + r0) * K + swzS;
  bf16* lA0 = &As[0][0] + r0 * 32 + c0 * 8;         // linear dest = tid*16B
  bf16* lB0 = &Bs[0][0] + r0 * 32 + c0 * 8;

#define STAGE_GT(buf, k0)                                                       \
  do {                                                                          \
    bf16* lA = lA0 + (buf) * (2 * 128 * 32);                                    \
    bf16* lB = lB0 + (buf) * (2 * TN * 32);                                     \
    glds16(Ap + (k0), lA);                                                      \
    glds16(Ap + (k0) + (size_t)64 * K, lA + 64 * 32);                           \
    glds16(Ap + (k0) + 32, lA + 128 * 32);                                      \
    glds16(Ap + (k0) + 32 + (size_t)64 * K, lA + 192 * 32);                     \
    glds16(Bp + (k0), lB);                                                      \
    if (TN == 128) glds16(Bp + (k0) + (size_t)64 * K, lB + 64 * 32);            \
    glds16(Bp + (k0) + 32, lB + TN * 32);                                       \
    if (TN == 128) glds16(Bp + (k0) + 32 + (size_t)64 * K, lB + TN * 32 + 64 * 32); \
  } while (0)

#define COMPUTE_GT(buf)                                                          \
  do {                                                                           \
    _Pragma("unroll")                                                            \
    for (int kp = 0; kp < 2; ++kp) {                                             \
      const bf16* Asp = &As[buf][0] + kp * 128 * 32;                             \
      const bf16* Bsp = &Bs[buf][0] + kp * TN * 32;                              \
      _Pragma("unroll")                                                          \
      for (int kh = 0; kh < 2; ++kh) {                                           \
        const int rc = ((kh * 2 + hi) ^ rsw) << 3;                               \
        bf16x8 af[2], bfr[CJ];                                                   \
        _Pragma("unroll")                                                        \
        for (int i = 0; i < 2; ++i)                                              \
          af[i] = *(const bf16x8*)(Asp + (mw + i * 32 + l31) * 32 + rc);         \
        _Pragma("unroll")                                                        \
        for (int j = 0; j < CJ; ++j)                                             \
          bfr[j] = *(const bf16x8*)(Bsp + (nw + j * 32 + l31) * 32 + rc);        \
        _Pragma("unroll")                                                        \
        for (int i = 0; i < 2; ++i)                                              \
          _Pragma("unroll")                                                      \
          for (int j = 0; j < CJ; ++j)                                           \
            acc[i][j] = __builtin_amdgcn_mfma_f32_32x32x16_bf16(af[i], bfr[j], acc[i][j], 0, 0, 0); \
      }                                                                          \
    }                                                                            \
  } while (0)

  if (DB == 2) {
    STAGE_GT(0, 0);
    __syncthreads();
    for (int k0 = 0; k0 < K; k0 += 64) {
      const int cur = (k0 >> 6) & 1;
      if (k0 + 64 < K) STAGE_GT(cur ^ 1, k0 + 64);
      COMPUTE_GT(cur);
      __syncthreads();
    }
  } else {
    for (int k0 = 0; k0 < K; k0 += 64) {
      __syncthreads();
      STAGE_GT(0, k0);
      __syncthreads();
      COMPUTE_GT(0);
    }
  }
#undef STAGE_GT
#undef COMPUTE_GT

#pragma unroll
  for (int i = 0; i < 2; ++i) {
    const int rb = m0 + mw + i * 32 + 4 * (lane >> 5);
#pragma unroll
    for (int j = 0; j < CJ; ++j) {
      const int col = n0 + nw + j * 32 + l31;
      const float bv = bias ? bias[col] : 0.f;
#pragma unroll
      for (int reg = 0; reg < 16; ++reg) {
        const int row = rb + (reg & 3) + 8 * (reg >> 2);
        const size_t off = (size_t)row * N + col;
        float v2 = acc[i][j][reg] + bv;
        if (res) v2 += res[off];
        if (Cf) Cf[off] = v2;
        if (Cb) Cb[off] = (bf16)v2;
      }
    }
  }
}

// ---------------- FF1: 8-phase 256-row x (128a+128g col) GLU GEMM, v2 with T2 swizzle ----------------
// Schedule identical to the R1-refcheck-passed version (T3+T4 counted vmcnt(6)
// at phases 4/8, T5 setprio, T1 XCD map). v2 fixed the R1 perf bug via the T2
// swizzle below; measured R6: bank conflicts 6.3e6 -> 0, 145 -> 94.2 us.
__global__ __launch_bounds__(512, 2) void k_glu8(const bf16* __restrict__ A,
                                                 const bf16* __restrict__ Bt,
                                                 const float* __restrict__ bias,
                                                 bf16* __restrict__ C) {
  constexpr int K = 1024, NOUT = 4096, NT = K / 64, NIT = NT / 2;
  __shared__ __align__(16) bf16 sA[2 * 2 * 8192];   // [buf][khalf][256][32]
  __shared__ __align__(16) bf16 sB[2 * 2 * 8192];

  const int bid = blockIdx.x;
  const int xcd = bid & 7, bj = bid >> 3;
  const int n_idx = xcd * 4 + (bj >> 4);
  const int m_idx = bj & 15;
  const int m0 = m_idx * 256, n0 = n_idx * 128;

  const int tid = threadIdx.x;
  const int wid = tid >> 6, lane = tid & 63;
  const int l15 = lane & 15, hi = lane >> 4;
  const int wm = wid >> 2, wn = wid & 3;     // 2 x 4 wave grid

  const int srA = wid * 32 + (lane >> 2);
  const int scol = ((lane & 3) ^ ((lane >> 3) & 3)) * 8;
  const bf16* aS0 = A + (size_t)(m0 + srA) * K + scol;
  const bf16* aS1 = aS0 + (size_t)16 * K;
  auto grow = [&](int r) {   // B LDS row -> global Bt row (a/gate interleave)
    return n0 + (r >> 6) * 32 + (r & 31) + ((r & 32) ? NOUT : 0);
  };
  const bf16* bS0 = Bt + (size_t)grow(srA) * K + scol;
  const bf16* bS1 = Bt + (size_t)grow(srA + 16) * K + scol;
  bf16* aD = sA + wid * 1024 + lane * 8;
  bf16* bD = sB + wid * 1024 + lane * 8;
  const int rxor = (hi ^ ((l15 >> 1) & 3)) * 8;   // read-side physical chunk
  const bf16* aF = sA + (wm * 128 + l15) * 32 + rxor;
  const bf16* bF = sB + (wn * 64 + l15) * 32 + rxor;

  f32x4 acc[8][4];
#pragma unroll
  for (int i = 0; i < 8; ++i)
#pragma unroll
    for (int n = 0; n < 4; ++n) acc[i][n] = (f32x4){0.f, 0.f, 0.f, 0.f};
  bf16x8 aq[4], bq[4];

#define STG_A(bb, kh, kt) do { \
    glds16(aS0 + (kt) * 64 + (kh) * 32, aD + ((bb) * 2 + (kh)) * 8192); \
    glds16(aS1 + (kt) * 64 + (kh) * 32, aD + ((bb) * 2 + (kh)) * 8192 + 512); } while (0)
#define STG_B(bb, kh, kt) do { \
    glds16(bS0 + (kt) * 64 + (kh) * 32, bD + ((bb) * 2 + (kh)) * 8192); \
    glds16(bS1 + (kt) * 64 + (kh) * 32, bD + ((bb) * 2 + (kh)) * 8192 + 512); } while (0)

#define PH(bb, kh, mh, STAGES, VMC) do { \
    if ((mh) == 0) { \
      _Pragma("unroll") \
      for (int nf = 0; nf < 4; ++nf) \
        bq[nf] = *(const bf16x8*)(bF + ((bb) * 2 + (kh)) * 8192 + nf * 512); \
    } \
    _Pragma("unroll") \
    for (int mi = 0; mi < 4; ++mi) \
      aq[mi] = *(const bf16x8*)(aF + ((bb) * 2 + (kh)) * 8192 + ((mh) * 4 + mi) * 512); \
    STAGES; \
    __builtin_amdgcn_s_barrier(); \
    asm volatile("s_waitcnt lgkmcnt(0)" ::: "memory"); \
    __builtin_amdgcn_sched_barrier(0); \
    __builtin_amdgcn_s_setprio(1); \
    _Pragma("unroll") \
    for (int mi = 0; mi < 4; ++mi) \
      _Pragma("unroll") \
      for (int nf = 0; nf < 4; ++nf) \
        acc[(mh) * 4 + mi][nf] = __builtin_amdgcn_mfma_f32_16x16x32_bf16( \
            aq[mi], bq[nf], acc[(mh) * 4 + mi][nf], 0, 0, 0); \
    __builtin_amdgcn_s_setprio(0); \
    VMC; \
    __builtin_amdgcn_s_barrier(); \
    __builtin_amdgcn_sched_barrier(0); \
  } while (0)

  // prologue: tile0 fully + tile1 {B-K0, A-K0, B-K1}; vmcnt(6) -> tile0 landed.
  STG_B(0, 0, 0); STG_A(0, 0, 0); STG_B(0, 1, 0); STG_A(0, 1, 0);
  STG_B(1, 0, 1); STG_A(1, 0, 1); STG_B(1, 1, 1);
  asm volatile("s_waitcnt vmcnt(6)" ::: "memory");
  __builtin_amdgcn_s_barrier();
  __builtin_amdgcn_sched_barrier(0);

  for (int it = 0; it < NIT; ++it) {
    const int T = 2 * it;
    const int t2 = (T + 2 < NT) ? (T + 2) : 0;   // clamped dead prefetch on tail
    const int t3 = (T + 3 < NT) ? (T + 3) : 0;
    PH(0, 0, 0, STG_A(1, 1, T + 1), );
    PH(0, 0, 1, STG_B(0, 0, t2), );
    PH(0, 1, 0, STG_A(0, 0, t2), );
    PH(0, 1, 1, STG_B(0, 1, t2), asm volatile("s_waitcnt vmcnt(6)" ::: "memory"));
    PH(1, 0, 0, STG_A(0, 1, t2), );
    PH(1, 0, 1, STG_B(1, 0, t3), );
    PH(1, 1, 0, STG_A(1, 0, t3), );
    PH(1, 1, 1, STG_B(1, 1, t3), asm volatile("s_waitcnt vmcnt(6)" ::: "memory"));
  }
#undef PH
#undef STG_A
#undef STG_B

  // GLU epilogue: acc[.][0..1] = a, acc[.][2..3] = gate for the same columns.
#pragma unroll
  for (int mi = 0; mi < 8; ++mi) {
    const int row = m0 + wm * 128 + mi * 16 + hi * 4;
#pragma unroll
    for (int nf = 0; nf < 2; ++nf) {
      const int col = n0 + wn * 32 + nf * 16 + l15;
      const float bav = bias[col], bgv = bias[NOUT + col];
#pragma unroll
      for (int r = 0; r < 4; ++r) {
        float a = acc[mi][nf][r] + bav;
        float g = acc[mi][nf + 2][r] + bgv;
        float ge = 0.5f * g * (1.0f + erff(g * 0.70710678118654752f));
        C[(size_t)(row + r) * NOUT + col] = (bf16)(a * ge);
      }
    }
  }
}

// ---------------- flash attention, fixed-max softmax, 128 Q-rows/block ----------------
// min-2-phase K/V pipeline + XOR-swizzled K/V tiles (measured R5: -7.5us total).
__global__ __launch_bounds__(256) void k_attn(const bf16* __restrict__ Qp, int qstride,
                                              const bf16* __restrict__ Kp, int kstride,
                                              const bf16* __restrict__ VTp,
                                              bf16* __restrict__ Op, int kvlen) {
  const int qt = blockIdx.x * 128;
  const int hd = blockIdx.y;
  const int b = blockIdx.z;
  const int tid = threadIdx.x;
  const int wave = tid >> 6, lane = tid & 63;
  const int quad = lane >> 4, l16 = lane & 15;
  const int rswq = l16 & 7;                  // read-side chunk XOR (row&7 of read row)

  __shared__ __align__(16) bf16 Ks[2][64 * 64];
  __shared__ __align__(16) bf16 Vs[2][64 * 64];
  __shared__ __align__(16) bf16 Ps[4][32 * 72];

  bf16x8 qf[2][2];
#pragma unroll
  for (int g = 0; g < 2; ++g) {
    const bf16* qrow = Qp + (size_t)(b * cS + qt + wave * 32 + g * 16 + l16) * qstride + hd * 64;
#pragma unroll
    for (int c = 0; c < 2; ++c) {
      bf16x8 raw = *(const bf16x8*)(qrow + c * 32 + quad * 8);
#pragma unroll
      for (int e = 0; e < 8; ++e) qf[g][c][e] = (bf16)((float)raw[e] * 0.125f);
    }
  }

  float l_part[2][4] = {{0.f, 0.f, 0.f, 0.f}, {0.f, 0.f, 0.f, 0.f}};
  f32x4 o_acc[2][4];
#pragma unroll
  for (int g = 0; g < 2; ++g)
#pragma unroll
    for (int n = 0; n < 4; ++n) o_acc[g][n] = (f32x4){0.f, 0.f, 0.f, 0.f};

  const int lrow = wave * 16 + (lane >> 3);                // staged row (row&7 = (lane>>3)&7)
  const int lcol = (lane & 7) * 8;                         // linear LDS dest chunk
  const int scol = (((lane & 7) ^ ((lane >> 3) & 7)) * 8); // inverse-swizzled global src
  const bf16* kbase = Kp + (size_t)(b * kvlen + lrow) * kstride + hd * 64 + scol;
  const bf16* vbase = VTp + ((size_t)((b * 16 + hd) * 64 + lrow)) * kvlen + scol;
  bf16* lk0 = &Ks[0][0] + lrow * 64 + lcol;
  bf16* lv0 = &Vs[0][0] + lrow * 64 + lcol;

#define STAGE_AT(buf, kt)                                              \
  do {                                                                 \
    const bf16* kg = kbase + (size_t)(kt) * kstride;                   \
    bf16* lk = lk0 + (buf) * (64 * 64);                                \
    bf16* lv = lv0 + (buf) * (64 * 64);                                \
    glds16(kg, lk);                                                    \
    glds16(kg + (size_t)8 * kstride, lk + 8 * 64);                     \
    glds16(vbase + (kt), lv);                                          \
    glds16(vbase + (kt) + (size_t)8 * kvlen, lv + 8 * 64);             \
  } while (0)

  STAGE_AT(0, 0);
  __syncthreads();

  for (int kt = 0; kt < kvlen; kt += 64) {
    const int cur = (kt >> 6) & 1;
    if (kt + 64 < kvlen) STAGE_AT(cur ^ 1, kt + 64);

    f32x4 s[2][4];
#pragma unroll
    for (int g = 0; g < 2; ++g)
#pragma unroll
      for (int t = 0; t < 4; ++t) s[g][t] = (f32x4){0.f, 0.f, 0.f, 0.f};
#pragma unroll
    for (int t = 0; t < 4; ++t)
#pragma unroll
      for (int c = 0; c < 2; ++c) {
        bf16x8 kf = *(const bf16x8*)(&Ks[cur][0] + (t * 16 + l16) * 64 + (((c * 4 + quad) ^ rswq) << 3));
#pragma unroll
        for (int g = 0; g < 2; ++g)
          s[g][t] = __builtin_amdgcn_mfma_f32_16x16x32_bf16(qf[g][c], kf, s[g][t], 0, 0, 0);
      }

#pragma unroll
    for (int g = 0; g < 2; ++g)
#pragma unroll
      for (int t = 0; t < 4; ++t)
#pragma unroll
        for (int r = 0; r < 4; ++r) {
          float p = __expf(s[g][t][r]);
          Ps[wave][(g * 16 + quad * 4 + r) * 72 + t * 16 + l16] = (bf16)p;
          l_part[g][r] += p;
        }

    bf16x8 pf[2][2];
#pragma unroll
    for (int g = 0; g < 2; ++g)
#pragma unroll
      for (int c = 0; c < 2; ++c)
        pf[g][c] = *(const bf16x8*)(&Ps[wave][(g * 16 + l16) * 72 + c * 32 + quad * 8]);
#pragma unroll
    for (int n = 0; n < 4; ++n)
#pragma unroll
      for (int c = 0; c < 2; ++c) {
        bf16x8 vf = *(const bf16x8*)(&Vs[cur][0] + (n * 16 + l16) * 64 + (((c * 4 + quad) ^ rswq) << 3));
#pragma unroll
        for (int g = 0; g < 2; ++g)
          o_acc[g][n] = __builtin_amdgcn_mfma_f32_16x16x32_bf16(pf[g][c], vf, o_acc[g][n], 0, 0, 0);
      }
    __syncthreads();
  }
#undef STAGE_AT

#pragma unroll
  for (int g = 0; g < 2; ++g) {
    float rl[4];
#pragma unroll
    for (int r = 0; r < 4; ++r) {
      float v = l_part[g][r];
      v += __shfl_xor(v, 1);
      v += __shfl_xor(v, 2);
      v += __shfl_xor(v, 4);
      v += __shfl_xor(v, 8);
      rl[r] = 1.f / v;
    }
#pragma unroll
    for (int n = 0; n < 4; ++n)
#pragma unroll
      for (int r = 0; r < 4; ++r) {
        const int srow = qt + wave * 32 + g * 16 + quad * 4 + r;
        const int d = n * 16 + l16;
        Op[(size_t)(b * cS + srow) * 1024 + hd * 64 + d] = (bf16)(o_acc[g][n][r] * rl[r]);
      }
  }
}

// ---------------- launch ----------------
extern "C" void kernel_launch(void* const* d_in, const int* in_sizes, int n_in,
                              void* d_out, int out_size, void* d_ws, size_t ws_size,
                              hipStream_t stream) {
  const float* x    = (const float*)d_in[0];
  const float* tt   = (const float*)d_in[1];
  const float* ctx  = (const float*)d_in[2];
  const float* fw1  = (const float*)d_in[13];
  const float* fb1  = (const float*)d_in[14];
  const float* fw2  = (const float*)d_in[15];
  const float* fb2  = (const float*)d_in[16];
  const float* a1bo = (const float*)d_in[7];
  const float* a2bo = (const float*)d_in[12];

  char* ws = (char*)d_ws;
  const size_t MB = 1ull << 20;
  // 8 square transposed weights packed: [q1,k1,v1,o1,q2,k2,v2,o2] x 2 MB
  bf16* wsq   = (bf16*)(ws + 0 * MB);
  bf16* wqkv1 = wsq;                               // mats 0-2
  bf16* wto1  = (bf16*)(ws + 6 * MB);              // mat 3
  bf16* wtq2  = (bf16*)(ws + 8 * MB);              // mat 4
  bf16* wkv2w = (bf16*)(ws + 10 * MB);             // mats 5-6
  bf16* wto2  = (bf16*)(ws + 14 * MB);             // mat 7
  bf16* wtf1  = (bf16*)(ws + 16 * MB);             // [8192,1024], 16 MB
  bf16* wtf2  = (bf16*)(ws + 32 * MB);             // [1024,4096], 8 MB
  float* emb  = (float*)(ws + 40 * MB);            // 3 x [2,2048]
  float* emb1 = emb, *emb2 = emb + 4096, *emb3 = emb + 8192;
  bf16* ctxb  = (bf16*)(ws + 40 * MB + 262144);    // [512,1024], 1 MB
  float* xres = (float*)(ws + 42 * MB);            // fp32 residual, 16 MB
  bf16* h     = (bf16*)(ws + 58 * MB);             // 8 MB
  bf16* ao    = h;
  bf16* qkv   = (bf16*)(ws + 66 * MB);             // [4096,3072], 24 MB
  bf16* q2    = qkv;
  bf16* vT1   = (bf16*)(ws + 90 * MB);             // [32*64,2048], 8 MB
  bf16* kv2   = (bf16*)(ws + 0 * MB);              // [512,2048], 2 MB (aliases dead mats 0-1)
  bf16* vT2   = (bf16*)(ws + 2 * MB);              // [32*64,256], 1 MB (aliases dead mat 1)
  bf16* g     = (bf16*)(ws + 66 * MB);             // [4096,4096], 32 MB
  float* out  = (float*)d_out;

  const dim3 blk(256);

  T8 t8;
  t8.s[0] = (const float*)d_in[3];   // a1wq
  t8.s[1] = (const float*)d_in[4];   // a1wk
  t8.s[2] = (const float*)d_in[5];   // a1wv
  t8.s[3] = (const float*)d_in[6];   // a1wo
  t8.s[4] = (const float*)d_in[8];   // a2wq
  t8.s[5] = (const float*)d_in[9];   // a2wk
  t8.s[6] = (const float*)d_in[10];  // a2wv
  t8.s[7] = (const float*)d_in[11];  // a2wo
  k_transpose8<<<dim3(16, 16, 8), blk, 0, stream>>>(t8, wsq);
  k_transpose<<<dim3(128, 16), blk, 0, stream>>>(fw1, wtf1, 1024, 8192);
  k_transpose<<<dim3(16, 64), blk, 0, stream>>>(fw2, wtf2, 4096, 1024);

  EmbArgs ea;
  ea.w0 = (const float*)d_in[17]; ea.b0 = (const float*)d_in[18];
  ea.w1 = (const float*)d_in[19]; ea.b1 = (const float*)d_in[20];
  ea.w2 = (const float*)d_in[21]; ea.b2 = (const float*)d_in[22];
  k_emb3<<<dim3(32, 3), blk, 0, stream>>>(tt, ea, emb);
  k_f2b<<<512, blk, 0, stream>>>(ctx, ctxb);

  // ---- block 1: self-attention ----
  k_adaln<<<4096, blk, 0, stream>>>(x, emb1, h);
  k_gemm_t<128, 1><<<dim3(24, 32), blk, 0, stream>>>(h, wqkv1, qkv, nullptr, nullptr, nullptr, 4096, 3072, 1024);
  k_vt<<<dim3(32, 32), blk, 0, stream>>>(qkv + 2048, 3072, vT1, 2048);
  k_attn<<<dim3(16, 16, 2), blk, 0, stream>>>(qkv, 3072, qkv + 1024, 3072, vT1, ao, 2048);
  k_gemm_t<64, 2><<<dim3(16, 32), blk, 0, stream>>>(ao, wto1, nullptr, xres, a1bo, x, 4096, 1024, 1024);

  // ---- block 2: cross-attention ----
  k_adaln<<<4096, blk, 0, stream>>>(xres, emb2, h);
  k_gemm_t<64, 2><<<dim3(16, 32), blk, 0, stream>>>(h, wtq2, q2, nullptr, nullptr, nullptr, 4096, 1024, 1024);
  k_gemm_t<128, 1><<<dim3(16, 4), blk, 0, stream>>>(ctxb, wkv2w, kv2, nullptr, nullptr, nullptr, 512, 2048, 1024);
  k_vt<<<dim3(4, 32), blk, 0, stream>>>(kv2 + 1024, 2048, vT2, 256);
  k_attn<<<dim3(16, 16, 2), blk, 0, stream>>>(q2, 1024, kv2, 2048, vT2, ao, 256);
  k_gemm_t<64, 2><<<dim3(16, 32), blk, 0, stream>>>(ao, wto2, nullptr, xres, a2bo, xres, 4096, 1024, 1024);

  // ---- block 3: gated-GELU FFN ----
  k_adaln<<<4096, blk, 0, stream>>>(xres, emb3, h);
  k_glu8<<<dim3(512), dim3(512), 0, stream>>>(h, wtf1, fb1, g);
  k_gemm_t<64, 2><<<dim3(16, 32), blk, 0, stream>>>(g, wtf2, nullptr, out, fb2, xres, 4096, 1024, 4096);
}